// Round 5
// baseline (453.482 us; speedup 1.0000x reference)
//
#include <hip/hip_runtime.h>
#include <stdint.h>

typedef unsigned short u16;
typedef __attribute__((ext_vector_type(8))) short bf16x8;
typedef __attribute__((ext_vector_type(4))) float f32x4;

__device__ __forceinline__ float b2f(u16 u) {
    union { float f; uint32_t u; } v; v.u = ((uint32_t)u) << 16; return v.f;
}
__device__ __forceinline__ u16 f2b(float f) {
    union { float f; uint32_t u; } v; v.f = f;
    uint32_t r = v.u + 0x7FFFu + ((v.u >> 16) & 1u);
    return (u16)(r >> 16);
}

// DPP cross-lane move within 16-lane rows (row_ror:N = 0x120+N). Full-rate VALU.
template <int CTRL>
__device__ __forceinline__ float dppf(float x) {
    union { float f; int i; } u; u.f = x;
    u.i = __builtin_amdgcn_update_dpp(0, u.i, CTRL, 0xF, 0xF, false);
    return u.f;
}
// all-lanes max/sum over each 16-lane DPP row via rotate-reduce
__device__ __forceinline__ float rowmax16(float v) {
    v = fmaxf(v, dppf<0x121>(v));   // ror 1
    v = fmaxf(v, dppf<0x122>(v));   // ror 2
    v = fmaxf(v, dppf<0x124>(v));   // ror 4
    v = fmaxf(v, dppf<0x128>(v));   // ror 8
    return v;
}
__device__ __forceinline__ float rowsum16(float v) {
    v += dppf<0x121>(v);
    v += dppf<0x122>(v);
    v += dppf<0x124>(v);
    v += dppf<0x128>(v);
    return v;
}

// async global->LDS, 16B/lane. LDS dest must be wave-uniform; HW adds lane*16.
__device__ __forceinline__ void stage16(const void* g, void* l) {
    __builtin_amdgcn_global_load_lds(
        (const __attribute__((address_space(1))) uint32_t*)(uintptr_t)g,
        (__attribute__((address_space(3))) uint32_t*)(uint32_t)(uintptr_t)l,
        16, 0, 0);
}

// ---- all 5 weight transposes in ONE launch: in (R x C) f32 -> out (C x R) bf16 ----
__global__ __launch_bounds__(256) void transpose_all(const float* __restrict__ Wqkv,
                                                     const float* __restrict__ Wattn,
                                                     const float* __restrict__ Wfc1,
                                                     const float* __restrict__ Wfc2,
                                                     const float* __restrict__ Wmlp,
                                                     u16* WtQ, u16* WtA, u16* WtF1,
                                                     u16* WtF2, u16* WtM) {
    __shared__ u16 tile[32][33];
    int id = blockIdx.x;
    const float* src; u16* dst; int R, C;
    if (id < 3072)      {             src = Wqkv;  dst = WtQ;  R = 1024; C = 3072; }
    else if (id < 4096) { id -= 3072; src = Wattn; dst = WtA;  R = 1024; C = 1024; }
    else if (id < 6912) { id -= 4096; src = Wfc1;  dst = WtF1; R = 1024; C = 2816; }
    else if (id < 9728) { id -= 6912; src = Wfc2;  dst = WtF2; R = 1024; C = 2816; }
    else                { id -= 9728; src = Wmlp;  dst = WtM;  R = 2816; C = 1024; }
    const int nbx = C >> 5;
    const int bx = id % nbx, by = id / nbx;
    const int cx = bx * 32, ry = by * 32;
    const int tx = threadIdx.x, ty = threadIdx.y; // 32 x 8
    #pragma unroll
    for (int i = 0; i < 32; i += 8)
        tile[ty + i][tx] = f2b(src[(size_t)(ry + ty + i) * C + cx + tx]);
    __syncthreads();
    #pragma unroll
    for (int i = 0; i < 32; i += 8)
        dst[(size_t)(cx + ty + i) * R + ry + tx] = tile[tx][ty + i];
}

// ---- rmsnorm (row = 1024): fp32 in, fp32 scale, bf16 out ----
__global__ __launch_bounds__(256) void rmsnorm_f32(const float* __restrict__ xin,
                                                   const float* __restrict__ scale,
                                                   u16* __restrict__ out) {
    const int row = blockIdx.x, tid = threadIdx.x;
    const float4 v = ((const float4*)(xin + (size_t)row * 1024))[tid];
    float ss = v.x * v.x + v.y * v.y + v.z * v.z + v.w * v.w;
    #pragma unroll
    for (int d = 32; d; d >>= 1) ss += __shfl_xor(ss, d);
    __shared__ float wsum[4];
    if ((tid & 63) == 0) wsum[tid >> 6] = ss;
    __syncthreads();
    const float r = rsqrtf((wsum[0] + wsum[1] + wsum[2] + wsum[3]) * (1.f / 1024.f) + 1e-5f);
    const float4 sc = ((const float4*)scale)[tid];
    uint2 o;
    o.x = (uint32_t)f2b(v.x * sc.x * r) | ((uint32_t)f2b(v.y * sc.y * r) << 16);
    o.y = (uint32_t)f2b(v.z * sc.z * r) | ((uint32_t)f2b(v.w * sc.w * r) << 16);
    ((uint2*)(out + (size_t)row * 1024))[tid] = o;
}

// ---- RoPE in place on q,k thirds of qkv (4096 x 3072 bf16) ----
// One thread per (row, i): trig computed ONCE, applied to 16 q-heads + 16 k-heads
// via coalesced u32 accesses (lanes 0..31 span i -> 128B contiguous per head).
__global__ __launch_bounds__(256) void rope_kernel(u16* __restrict__ qkv) {
    const int gid = blockIdx.x * 256 + threadIdx.x;  // 131072 = 4096 rows * 32 i
    const int i = gid & 31;
    const int row = gid >> 5;
    const int tpos = row & 2047;
    const float theta = expf(-(float)i * (9.210340371976184f / 32.0f));
    const float ang = (float)tpos * theta;
    const float c = cosf(ang), s = sinf(ang);
    uint32_t* p = (uint32_t*)qkv + (size_t)row * 1536 + i;
    #pragma unroll
    for (int h = 0; h < 16; ++h) {
        const uint32_t uq = p[h * 32];
        {
            const float xe = b2f((u16)(uq & 0xffff)), xo = b2f((u16)(uq >> 16));
            p[h * 32] = (uint32_t)f2b(xe * c - xo * s) |
                        ((uint32_t)f2b(xe * s + xo * c) << 16);
        }
        const uint32_t uk = p[512 + h * 32];
        {
            const float xe = b2f((u16)(uk & 0xffff)), xo = b2f((u16)(uk >> 16));
            p[512 + h * 32] = (uint32_t)f2b(xe * c - xo * s) |
                              ((uint32_t)f2b(xe * s + xo * c) << 16);
        }
    }
}

// ---- GEMM: A (M x K) bf16, Bt (N x K) bf16, 128x128 tile, 2x BK=32 halves per
// barrier pair (8 stage16 in flight, 32 MFMA per drain -> half the barrier stalls).
// EPI 0: Cbf16 = f2b(acc);  EPI 1: Cf32 = acc + Res_f32;  EPI 2: Cbf16 = silu(Res_bf16)*acc
template <int EPI>
__global__ __launch_bounds__(256) void gemm_bt(const u16* __restrict__ A,
                                               const u16* __restrict__ Bt,
                                               void* __restrict__ Cout,
                                               const void* __restrict__ Res,
                                               int N, int K) {
    __shared__ __attribute__((aligned(16))) u16 As[2][128 * 32];
    __shared__ __attribute__((aligned(16))) u16 Bs[2][128 * 32];
    const int tid = threadIdx.x;
    const int w = tid >> 6, lane = tid & 63;
    const int quad = lane >> 4, t = lane & 15;
    const int m0 = blockIdx.y * 128, n0 = blockIdx.x * 128;
    const int wm = (w >> 1) * 64, wn = (w & 1) * 64;

    const int srow = w * 16 + (lane >> 2);
    const int scol = (lane & 3) * 8;
    const u16* pA0 = A + (size_t)(m0 + srow) * K + scol;
    const u16* pA1 = pA0 + (size_t)64 * K;
    const u16* pB0 = Bt + (size_t)(n0 + srow) * K + scol;
    const u16* pB1 = pB0 + (size_t)64 * K;

    f32x4 acc[4][4];
    #pragma unroll
    for (int i = 0; i < 4; ++i)
        #pragma unroll
        for (int j = 0; j < 4; ++j) acc[i][j] = (f32x4){0.f, 0.f, 0.f, 0.f};

    for (int kb = 0; kb < K; kb += 64) {
        __syncthreads();                 // prior iteration's LDS reads complete
        stage16(pA0 + kb,      (char*)As[0] + w * 1024);
        stage16(pA1 + kb,      (char*)As[0] + 4096 + w * 1024);
        stage16(pB0 + kb,      (char*)Bs[0] + w * 1024);
        stage16(pB1 + kb,      (char*)Bs[0] + 4096 + w * 1024);
        stage16(pA0 + kb + 32, (char*)As[1] + w * 1024);
        stage16(pA1 + kb + 32, (char*)As[1] + 4096 + w * 1024);
        stage16(pB0 + kb + 32, (char*)Bs[1] + w * 1024);
        stage16(pB1 + kb + 32, (char*)Bs[1] + 4096 + w * 1024);
        __syncthreads();                 // vmcnt(0) drain: staging visible
        #pragma unroll
        for (int hf = 0; hf < 2; ++hf) {
            bf16x8 af[4], bfr[4];
            #pragma unroll
            for (int mi = 0; mi < 4; ++mi)
                af[mi] = *(const bf16x8*)((char*)As[hf] + (wm + mi * 16 + t) * 64 + quad * 16);
            #pragma unroll
            for (int ni = 0; ni < 4; ++ni)
                bfr[ni] = *(const bf16x8*)((char*)Bs[hf] + (wn + ni * 16 + t) * 64 + quad * 16);
            #pragma unroll
            for (int mi = 0; mi < 4; ++mi)
                #pragma unroll
                for (int ni = 0; ni < 4; ++ni)
                    acc[mi][ni] = __builtin_amdgcn_mfma_f32_16x16x32_bf16(af[mi], bfr[ni],
                                                                         acc[mi][ni], 0, 0, 0);
        }
    }
    #pragma unroll
    for (int mi = 0; mi < 4; ++mi) {
        const int row0 = m0 + wm + mi * 16 + quad * 4;
        #pragma unroll
        for (int ni = 0; ni < 4; ++ni) {
            const int col = n0 + wn + ni * 16 + t;
            #pragma unroll
            for (int r = 0; r < 4; ++r) {
                const size_t idx = (size_t)(row0 + r) * N + col;
                const float v = acc[mi][ni][r];
                if (EPI == 0) {
                    ((u16*)Cout)[idx] = f2b(v);
                } else if (EPI == 1) {
                    ((float*)Cout)[idx] = v + ((const float*)Res)[idx];
                } else {
                    const float av = b2f(((const u16*)Res)[idx]);
                    ((u16*)Cout)[idx] = f2b((av / (1.f + __expf(-av))) * v);
                }
            }
        }
    }
}

// ---- GEMM variant: 128x64 tile for N=1024 shapes (512 blocks -> 2 blocks/CU),
// same 2x BK=32 unroll ----
template <int EPI>
__global__ __launch_bounds__(256) void gemm_bt64(const u16* __restrict__ A,
                                                 const u16* __restrict__ Bt,
                                                 void* __restrict__ Cout,
                                                 const float* __restrict__ Res,
                                                 int N, int K) {
    __shared__ __attribute__((aligned(16))) u16 As[2][128 * 32];  // 16 KB
    __shared__ __attribute__((aligned(16))) u16 Bs[2][64 * 32];   // 8 KB
    const int tid = threadIdx.x;
    const int w = tid >> 6, lane = tid & 63;
    const int quad = lane >> 4, t = lane & 15;
    const int m0 = blockIdx.y * 128, n0 = blockIdx.x * 64;
    const int wm = (w >> 1) * 64, wn = (w & 1) * 32;

    const int srow = w * 16 + (lane >> 2);
    const int scol = (lane & 3) * 8;
    const u16* pA0 = A + (size_t)(m0 + srow) * K + scol;
    const u16* pA1 = pA0 + (size_t)64 * K;
    const u16* pB0 = Bt + (size_t)(n0 + srow) * K + scol;

    f32x4 acc[4][2];
    #pragma unroll
    for (int i = 0; i < 4; ++i)
        #pragma unroll
        for (int j = 0; j < 2; ++j) acc[i][j] = (f32x4){0.f, 0.f, 0.f, 0.f};

    for (int kb = 0; kb < K; kb += 64) {
        __syncthreads();
        stage16(pA0 + kb,      (char*)As[0] + w * 1024);
        stage16(pA1 + kb,      (char*)As[0] + 4096 + w * 1024);
        stage16(pB0 + kb,      (char*)Bs[0] + w * 1024);
        stage16(pA0 + kb + 32, (char*)As[1] + w * 1024);
        stage16(pA1 + kb + 32, (char*)As[1] + 4096 + w * 1024);
        stage16(pB0 + kb + 32, (char*)Bs[1] + w * 1024);
        __syncthreads();
        #pragma unroll
        for (int hf = 0; hf < 2; ++hf) {
            bf16x8 af[4], bfr[2];
            #pragma unroll
            for (int mi = 0; mi < 4; ++mi)
                af[mi] = *(const bf16x8*)((char*)As[hf] + (wm + mi * 16 + t) * 64 + quad * 16);
            #pragma unroll
            for (int ni = 0; ni < 2; ++ni)
                bfr[ni] = *(const bf16x8*)((char*)Bs[hf] + (wn + ni * 16 + t) * 64 + quad * 16);
            #pragma unroll
            for (int mi = 0; mi < 4; ++mi)
                #pragma unroll
                for (int ni = 0; ni < 2; ++ni)
                    acc[mi][ni] = __builtin_amdgcn_mfma_f32_16x16x32_bf16(af[mi], bfr[ni],
                                                                         acc[mi][ni], 0, 0, 0);
        }
    }
    #pragma unroll
    for (int mi = 0; mi < 4; ++mi) {
        const int row0 = m0 + wm + mi * 16 + quad * 4;
        #pragma unroll
        for (int ni = 0; ni < 2; ++ni) {
            const int col = n0 + wn + ni * 16 + t;
            #pragma unroll
            for (int r = 0; r < 4; ++r) {
                const size_t idx = (size_t)(row0 + r) * N + col;
                const float v = acc[mi][ni][r];
                if (EPI == 0) ((u16*)Cout)[idx]   = f2b(v);
                else          ((float*)Cout)[idx] = v + Res[idx];
            }
        }
    }
}

// ---- flash attention: qkv (4096 x 3072 bf16, roped), y (4096 x 1024 bf16) ----
// K loaded DIRECTLY from global into MFMA fragments (wave-independent layout, L2-hot)
// -> no K LDS staging. Freed LDS double-buffers V within the same 28 KB footprint:
// ONE barrier per K-tile, next-V + K-frag loads issued at iteration top (latency
// hides under QK/softmax/PV). DPP softmax; diagonal-only mask; folded Q-scale.
// Vts XOR-swizzled: V[key][d] at row d, block (key>>3)^(d>>3), elem key&7.
__global__ __launch_bounds__(256) void attn_kernel(const u16* __restrict__ qkv,
                                                   const int* __restrict__ ymask,
                                                   u16* __restrict__ y) {
    const int qt = 31 - blockIdx.x;          // longest-first for tail occupancy
    const int h = blockIdx.y, b = blockIdx.z;
    const int tid = threadIdx.x;
    const int w = tid >> 6, lane = tid & 63;
    const int quad = lane >> 4, t = lane & 15;
    const int q0 = qt * 64;

    __shared__ __attribute__((aligned(16))) u16 Vts[2][64 * 72];  // [d][key], swizzled
    __shared__ __attribute__((aligned(16))) u16 Ps[4][16 * 72];   // per-wave P [m][key]
    __shared__ int ymL[64];
    if (qt == 0 && tid < 64) ymL[tid] = ymask[b * 64 + tid];

    bf16x8 aQ[2];
    {
        const u16* qp = qkv + (size_t)(b * 2048 + q0 + w * 16 + t) * 3072 + h * 64 + quad * 8;
        aQ[0] = *(const bf16x8*)qp;
        aQ[1] = *(const bf16x8*)(qp + 32);
        #pragma unroll
        for (int i = 0; i < 8; ++i) {   // fold 1/sqrt(64): *2^-3 exact in bf16
            aQ[0][i] = (short)f2b(b2f((u16)aQ[0][i]) * 0.125f);
            aQ[1][i] = (short)f2b(b2f((u16)aQ[1][i]) * 0.125f);
        }
    }

    // V staging assignment: thread -> (key = tid>>3 and +32, dg = tid&7)
    const int skey = tid >> 3, sdg = tid & 7;
    const u16* pV = qkv + (size_t)(b * 2048 + skey) * 3072 + h * 64 + sdg * 8 + 2048;
    const int sblk0 = (skey >> 3) ^ sdg;          // Vts block for keys 0..31 set
    const int sblk1 = (4 + (skey >> 3)) ^ sdg;    // keys 32..63 set

    // K fragment base: lane reads K row (kb*64 + ni*16 + t), d = quad*8 (+32 for bK1)
    const u16* pKf = qkv + (size_t)(b * 2048 + t) * 3072 + h * 64 + 1024 + quad * 8;

    // ---- prologue: stage V tile 0 into buffer 0 ----
    {
        const uint4 vv0 = *(const uint4*)pV;
        const uint4 vv1 = *(const uint4*)(pV + 98304);   // +32*3072
        const u16* vp0 = (const u16*)&vv0;
        const u16* vp1 = (const u16*)&vv1;
        #pragma unroll
        for (int jj = 0; jj < 8; ++jj) {
            const int row = sdg * 8 + jj;
            Vts[0][row * 72 + sblk0 * 8 + (skey & 7)] = vp0[jj];
            Vts[0][row * 72 + sblk1 * 8 + (skey & 7)] = vp1[jj];
        }
    }
    __syncthreads();

    f32x4 accO[4] = {(f32x4){0,0,0,0},(f32x4){0,0,0,0},(f32x4){0,0,0,0},(f32x4){0,0,0,0}};
    float mOld[4] = {-INFINITY, -INFINITY, -INFINITY, -INFINITY};
    float lSum[4] = {0.f, 0.f, 0.f, 0.f};

    int cur = 0;
    for (int kb = 0; kb <= qt; ++kb) {
        const bool more = (kb < qt);
        // next V tile loads issued first: latency hides under this tile's compute
        uint4 nv0, nv1;
        if (more) {
            const u16* pv = pV + (size_t)(kb + 1) * 196608;   // (kb+1)*64*3072
            nv0 = *(const uint4*)pv;
            nv1 = *(const uint4*)(pv + 98304);
        }
        // K fragments direct from global (L2-hot; wave-independent layout)
        const u16* pk = pKf + (size_t)kb * 196608;
        bf16x8 bK0[4], bK1[4];
        #pragma unroll
        for (int ni = 0; ni < 4; ++ni) {
            bK0[ni] = *(const bf16x8*)(pk + (size_t)ni * 49152);        // ni*16*3072
            bK1[ni] = *(const bf16x8*)(pk + (size_t)ni * 49152 + 32);
        }

        float s[4][4];
        __builtin_amdgcn_s_setprio(1);
        #pragma unroll
        for (int ni = 0; ni < 4; ++ni) {
            f32x4 sa = (f32x4){0.f, 0.f, 0.f, 0.f};
            sa = __builtin_amdgcn_mfma_f32_16x16x32_bf16(aQ[0], bK0[ni], sa, 0, 0, 0);
            sa = __builtin_amdgcn_mfma_f32_16x16x32_bf16(aQ[1], bK1[ni], sa, 0, 0, 0);
            #pragma unroll
            for (int r = 0; r < 4; ++r) s[ni][r] = sa[r];
        }
        __builtin_amdgcn_s_setprio(0);

        // mask only on the diagonal tile; ym text-mask only exists in the qt==0 tile.
        if (kb == qt) {
            const int irow = q0 + w * 16 + quad * 4;
            #pragma unroll
            for (int ni = 0; ni < 4; ++ni)
                #pragma unroll
                for (int r = 0; r < 4; ++r) {
                    const int i = irow + r, j = kb * 64 + ni * 16 + t;
                    const bool ok = (j <= i) || (qt == 0 && ymL[i & 63] && ymL[j & 63]);
                    if (!ok) s[ni][r] = -INFINITY;
                }
        }

        float alpha[4];
        bool upd = false;
        #pragma unroll
        for (int r = 0; r < 4; ++r) {
            float mt = fmaxf(fmaxf(s[0][r], s[1][r]), fmaxf(s[2][r], s[3][r]));
            mt = rowmax16(mt);                       // DPP, VALU-rate
            const float mNew = fmaxf(mOld[r], mt);
            upd = upd || (mNew > mOld[r]);
            alpha[r] = __expf(mOld[r] - mNew);
            #pragma unroll
            for (int ni = 0; ni < 4; ++ni) s[ni][r] = __expf(s[ni][r] - mNew);
            mOld[r] = mNew;
        }

        // P (C-layout) -> per-wave LDS, issued early; ds_write latency hides
        // under the DPP sum-reduces below. Same-wave, no barrier needed.
        u16* Pw = Ps[w];
        #pragma unroll
        for (int ni = 0; ni < 4; ++ni)
            #pragma unroll
            for (int r = 0; r < 4; ++r)
                Pw[(quad * 4 + r) * 72 + ni * 16 + t] = f2b(s[ni][r]);

        #pragma unroll
        for (int r = 0; r < 4; ++r) {
            float rs = (s[0][r] + s[1][r]) + (s[2][r] + s[3][r]);
            rs = rowsum16(rs);                       // DPP, VALU-rate
            lSum[r] = lSum[r] * alpha[r] + rs;
        }
        if (__any(upd)) {               // skip O-rescale when no row's max moved
            #pragma unroll
            for (int dt = 0; dt < 4; ++dt)
                #pragma unroll
                for (int r = 0; r < 4; ++r) accO[dt][r] *= alpha[r];
        }

        bf16x8 aP0 = *(const bf16x8*)((char*)Pw + t * 144 + quad * 16);
        bf16x8 aP1 = *(const bf16x8*)((char*)Pw + t * 144 + 64 + quad * 16);
        const u16* VtsC = Vts[cur];
        __builtin_amdgcn_s_setprio(1);
        #pragma unroll
        for (int dt = 0; dt < 4; ++dt) {
            const int row = dt * 16 + t, rb = row >> 3;
            bf16x8 bV0 = *(const bf16x8*)((const char*)VtsC + row * 144 + ((quad ^ rb) << 4));
            bf16x8 bV1 = *(const bf16x8*)((const char*)VtsC + row * 144 + (((4 + quad) ^ rb) << 4));
            accO[dt] = __builtin_amdgcn_mfma_f32_16x16x32_bf16(aP0, bV0, accO[dt], 0, 0, 0);
            accO[dt] = __builtin_amdgcn_mfma_f32_16x16x32_bf16(aP1, bV1, accO[dt], 0, 0, 0);
        }
        __builtin_amdgcn_s_setprio(0);

        if (!more) break;
        // stage next V tile into the other buffer; prior-iteration reads of that
        // buffer completed before the PREVIOUS end-of-iter barrier.
        {
            u16* VtsN = Vts[cur ^ 1];
            const u16* vp0 = (const u16*)&nv0;
            const u16* vp1 = (const u16*)&nv1;
            #pragma unroll
            for (int jj = 0; jj < 8; ++jj) {
                const int row = sdg * 8 + jj;
                VtsN[row * 72 + sblk0 * 8 + (skey & 7)] = vp0[jj];
                VtsN[row * 72 + sblk1 * 8 + (skey & 7)] = vp1[jj];
            }
        }
        __syncthreads();                 // single barrier per K-tile
        cur ^= 1;
    }
    const int orow = q0 + w * 16 + quad * 4;
    #pragma unroll
    for (int dt = 0; dt < 4; ++dt)
        #pragma unroll
        for (int r = 0; r < 4; ++r) {
            const size_t idx = (size_t)(b * 2048 + orow + r) * 1024 + h * 64 + dt * 16 + t;
            y[idx] = f2b(accO[dt][r] / lSum[r]);
        }
}

extern "C" void kernel_launch(void* const* d_in, const int* in_sizes, int n_in,
                              void* d_out, int out_size, void* d_ws, size_t ws_size,
                              hipStream_t stream) {
    const float* x     = (const float*)d_in[0];
    const int*   ym    = (const int*)d_in[1];
    const float* Wqkv  = (const float*)d_in[2];
    const float* Wattn = (const float*)d_in[3];
    const float* s1    = (const float*)d_in[4];
    const float* s2    = (const float*)d_in[5];
    const float* Wfc1  = (const float*)d_in[6];
    const float* Wfc2  = (const float*)d_in[7];
    const float* Wmlp  = (const float*)d_in[8];

    char* ws = (char*)d_ws;
    u16*   h    = (u16*)(ws + 0);          // 8 MB bf16; reused as attention output
    u16*   qkv  = (u16*)(ws + 8388608);    // 24 MB bf16; later reused as fc1/m
    u16*   fc1  = qkv;
    float* xr   = (float*)(ws + 33554432); // 16 MB fp32 residual
    u16*   WtA  = (u16*)(ws + 50331648);   // 2 MB
    u16*   WtF1 = (u16*)(ws + 52428800);   // 5.5 MB
    u16*   WtF2 = (u16*)(ws + 58195968);   // 5.5 MB
    u16*   WtM  = (u16*)(ws + 63963136);   // 5.5 MB
    u16*   WtQ  = (u16*)(ws + 73400320);   // 6 MB
    const dim3 tb(32, 8);

    transpose_all<<<12544, tb, 0, stream>>>(Wqkv, Wattn, Wfc1, Wfc2, Wmlp,
                                            WtQ, WtA, WtF1, WtF2, WtM);
    rmsnorm_f32<<<4096, 256, 0, stream>>>(x, s1, h);
    gemm_bt<0><<<dim3(24, 32), 256, 0, stream>>>(h, WtQ, qkv, nullptr, 3072, 1024);
    rope_kernel<<<512, 256, 0, stream>>>(qkv);
    attn_kernel<<<dim3(32, 16, 2), 256, 0, stream>>>(qkv, ym, h);   // h dead -> y
    gemm_bt64<1><<<dim3(16, 32), 256, 0, stream>>>(h, WtA, xr, x, 1024, 1024);
    rmsnorm_f32<<<4096, 256, 0, stream>>>(xr, s2, h);
    gemm_bt<0><<<dim3(22, 32), 256, 0, stream>>>(h, WtF1, fc1, nullptr, 2816, 1024);
    gemm_bt<2><<<dim3(22, 32), 256, 0, stream>>>(h, WtF2, fc1, fc1, 2816, 1024);
    gemm_bt64<1><<<dim3(16, 32), 256, 0, stream>>>(fc1, WtM, (float*)d_out, xr, 1024, 2816);
}

// Round 6
// 372.169 us; speedup vs baseline: 1.2185x; 1.2185x over previous
//
#include <hip/hip_runtime.h>
#include <stdint.h>

typedef unsigned short u16;
typedef __attribute__((ext_vector_type(8))) short bf16x8;
typedef __attribute__((ext_vector_type(4))) float f32x4;

__device__ __forceinline__ float b2f(u16 u) {
    union { float f; uint32_t u; } v; v.u = ((uint32_t)u) << 16; return v.f;
}
__device__ __forceinline__ u16 f2b(float f) {
    union { float f; uint32_t u; } v; v.f = f;
    uint32_t r = v.u + 0x7FFFu + ((v.u >> 16) & 1u);
    return (u16)(r >> 16);
}

// DPP cross-lane move within 16-lane rows (row_ror:N = 0x120+N). Full-rate VALU.
template <int CTRL>
__device__ __forceinline__ float dppf(float x) {
    union { float f; int i; } u; u.f = x;
    u.i = __builtin_amdgcn_update_dpp(0, u.i, CTRL, 0xF, 0xF, false);
    return u.f;
}
// all-lanes max/sum over each 16-lane DPP row via rotate-reduce
__device__ __forceinline__ float rowmax16(float v) {
    v = fmaxf(v, dppf<0x121>(v));   // ror 1
    v = fmaxf(v, dppf<0x122>(v));   // ror 2
    v = fmaxf(v, dppf<0x124>(v));   // ror 4
    v = fmaxf(v, dppf<0x128>(v));   // ror 8
    return v;
}
__device__ __forceinline__ float rowsum16(float v) {
    v += dppf<0x121>(v);
    v += dppf<0x122>(v);
    v += dppf<0x124>(v);
    v += dppf<0x128>(v);
    return v;
}

// async global->LDS, 16B/lane. LDS dest must be wave-uniform; HW adds lane*16.
__device__ __forceinline__ void stage16(const void* g, void* l) {
    __builtin_amdgcn_global_load_lds(
        (const __attribute__((address_space(1))) uint32_t*)(uintptr_t)g,
        (__attribute__((address_space(3))) uint32_t*)(uint32_t)(uintptr_t)l,
        16, 0, 0);
}

// ---- all 5 weight transposes in ONE launch: in (R x C) f32 -> out (C x R) bf16 ----
__global__ __launch_bounds__(256) void transpose_all(const float* __restrict__ Wqkv,
                                                     const float* __restrict__ Wattn,
                                                     const float* __restrict__ Wfc1,
                                                     const float* __restrict__ Wfc2,
                                                     const float* __restrict__ Wmlp,
                                                     u16* WtQ, u16* WtA, u16* WtF1,
                                                     u16* WtF2, u16* WtM) {
    __shared__ u16 tile[32][33];
    int id = blockIdx.x;
    const float* src; u16* dst; int R, C;
    if (id < 3072)      {             src = Wqkv;  dst = WtQ;  R = 1024; C = 3072; }
    else if (id < 4096) { id -= 3072; src = Wattn; dst = WtA;  R = 1024; C = 1024; }
    else if (id < 6912) { id -= 4096; src = Wfc1;  dst = WtF1; R = 1024; C = 2816; }
    else if (id < 9728) { id -= 6912; src = Wfc2;  dst = WtF2; R = 1024; C = 2816; }
    else                { id -= 9728; src = Wmlp;  dst = WtM;  R = 2816; C = 1024; }
    const int nbx = C >> 5;
    const int bx = id % nbx, by = id / nbx;
    const int cx = bx * 32, ry = by * 32;
    const int tx = threadIdx.x, ty = threadIdx.y; // 32 x 8
    #pragma unroll
    for (int i = 0; i < 32; i += 8)
        tile[ty + i][tx] = f2b(src[(size_t)(ry + ty + i) * C + cx + tx]);
    __syncthreads();
    #pragma unroll
    for (int i = 0; i < 32; i += 8)
        dst[(size_t)(cx + ty + i) * R + ry + tx] = tile[tx][ty + i];
}

// ---- rmsnorm (row = 1024): fp32 in, fp32 scale, bf16 out ----
__global__ __launch_bounds__(256) void rmsnorm_f32(const float* __restrict__ xin,
                                                   const float* __restrict__ scale,
                                                   u16* __restrict__ out) {
    const int row = blockIdx.x, tid = threadIdx.x;
    const float4 v = ((const float4*)(xin + (size_t)row * 1024))[tid];
    float ss = v.x * v.x + v.y * v.y + v.z * v.z + v.w * v.w;
    #pragma unroll
    for (int d = 32; d; d >>= 1) ss += __shfl_xor(ss, d);
    __shared__ float wsum[4];
    if ((tid & 63) == 0) wsum[tid >> 6] = ss;
    __syncthreads();
    const float r = rsqrtf((wsum[0] + wsum[1] + wsum[2] + wsum[3]) * (1.f / 1024.f) + 1e-5f);
    const float4 sc = ((const float4*)scale)[tid];
    uint2 o;
    o.x = (uint32_t)f2b(v.x * sc.x * r) | ((uint32_t)f2b(v.y * sc.y * r) << 16);
    o.y = (uint32_t)f2b(v.z * sc.z * r) | ((uint32_t)f2b(v.w * sc.w * r) << 16);
    ((uint2*)(out + (size_t)row * 1024))[tid] = o;
}

// ---- RoPE in place on q,k thirds of qkv (4096 x 3072 bf16) ----
// One thread per (row, i): trig computed ONCE, applied to 16 q-heads + 16 k-heads
// via coalesced u32 accesses (lanes 0..31 span i -> 128B contiguous per head).
__global__ __launch_bounds__(256) void rope_kernel(u16* __restrict__ qkv) {
    const int gid = blockIdx.x * 256 + threadIdx.x;  // 131072 = 4096 rows * 32 i
    const int i = gid & 31;
    const int row = gid >> 5;
    const int tpos = row & 2047;
    const float theta = expf(-(float)i * (9.210340371976184f / 32.0f));
    const float ang = (float)tpos * theta;
    const float c = cosf(ang), s = sinf(ang);
    uint32_t* p = (uint32_t*)qkv + (size_t)row * 1536 + i;
    #pragma unroll
    for (int h = 0; h < 16; ++h) {
        const uint32_t uq = p[h * 32];
        {
            const float xe = b2f((u16)(uq & 0xffff)), xo = b2f((u16)(uq >> 16));
            p[h * 32] = (uint32_t)f2b(xe * c - xo * s) |
                        ((uint32_t)f2b(xe * s + xo * c) << 16);
        }
        const uint32_t uk = p[512 + h * 32];
        {
            const float xe = b2f((u16)(uk & 0xffff)), xo = b2f((u16)(uk >> 16));
            p[512 + h * 32] = (uint32_t)f2b(xe * c - xo * s) |
                              ((uint32_t)f2b(xe * s + xo * c) << 16);
        }
    }
}

// ---- GEMM: A (M x K) bf16, Bt (N x K) bf16, 128x128 tile, 2x BK=32 halves per
// barrier pair (8 stage16 in flight, 32 MFMA per drain -> half the barrier stalls).
// EPI 0: Cbf16 = f2b(acc);  EPI 1: Cf32 = acc + Res_f32;  EPI 2: Cbf16 = silu(Res_bf16)*acc
template <int EPI>
__global__ __launch_bounds__(256) void gemm_bt(const u16* __restrict__ A,
                                               const u16* __restrict__ Bt,
                                               void* __restrict__ Cout,
                                               const void* __restrict__ Res,
                                               int N, int K) {
    __shared__ __attribute__((aligned(16))) u16 As[2][128 * 32];
    __shared__ __attribute__((aligned(16))) u16 Bs[2][128 * 32];
    const int tid = threadIdx.x;
    const int w = tid >> 6, lane = tid & 63;
    const int quad = lane >> 4, t = lane & 15;
    const int m0 = blockIdx.y * 128, n0 = blockIdx.x * 128;
    const int wm = (w >> 1) * 64, wn = (w & 1) * 64;

    const int srow = w * 16 + (lane >> 2);
    const int scol = (lane & 3) * 8;
    const u16* pA0 = A + (size_t)(m0 + srow) * K + scol;
    const u16* pA1 = pA0 + (size_t)64 * K;
    const u16* pB0 = Bt + (size_t)(n0 + srow) * K + scol;
    const u16* pB1 = pB0 + (size_t)64 * K;

    f32x4 acc[4][4];
    #pragma unroll
    for (int i = 0; i < 4; ++i)
        #pragma unroll
        for (int j = 0; j < 4; ++j) acc[i][j] = (f32x4){0.f, 0.f, 0.f, 0.f};

    for (int kb = 0; kb < K; kb += 64) {
        __syncthreads();                 // prior iteration's LDS reads complete
        stage16(pA0 + kb,      (char*)As[0] + w * 1024);
        stage16(pA1 + kb,      (char*)As[0] + 4096 + w * 1024);
        stage16(pB0 + kb,      (char*)Bs[0] + w * 1024);
        stage16(pB1 + kb,      (char*)Bs[0] + 4096 + w * 1024);
        stage16(pA0 + kb + 32, (char*)As[1] + w * 1024);
        stage16(pA1 + kb + 32, (char*)As[1] + 4096 + w * 1024);
        stage16(pB0 + kb + 32, (char*)Bs[1] + w * 1024);
        stage16(pB1 + kb + 32, (char*)Bs[1] + 4096 + w * 1024);
        __syncthreads();                 // vmcnt(0) drain: staging visible
        #pragma unroll
        for (int hf = 0; hf < 2; ++hf) {
            bf16x8 af[4], bfr[4];
            #pragma unroll
            for (int mi = 0; mi < 4; ++mi)
                af[mi] = *(const bf16x8*)((char*)As[hf] + (wm + mi * 16 + t) * 64 + quad * 16);
            #pragma unroll
            for (int ni = 0; ni < 4; ++ni)
                bfr[ni] = *(const bf16x8*)((char*)Bs[hf] + (wn + ni * 16 + t) * 64 + quad * 16);
            #pragma unroll
            for (int mi = 0; mi < 4; ++mi)
                #pragma unroll
                for (int ni = 0; ni < 4; ++ni)
                    acc[mi][ni] = __builtin_amdgcn_mfma_f32_16x16x32_bf16(af[mi], bfr[ni],
                                                                         acc[mi][ni], 0, 0, 0);
        }
    }
    #pragma unroll
    for (int mi = 0; mi < 4; ++mi) {
        const int row0 = m0 + wm + mi * 16 + quad * 4;
        #pragma unroll
        for (int ni = 0; ni < 4; ++ni) {
            const int col = n0 + wn + ni * 16 + t;
            #pragma unroll
            for (int r = 0; r < 4; ++r) {
                const size_t idx = (size_t)(row0 + r) * N + col;
                const float v = acc[mi][ni][r];
                if (EPI == 0) {
                    ((u16*)Cout)[idx] = f2b(v);
                } else if (EPI == 1) {
                    ((float*)Cout)[idx] = v + ((const float*)Res)[idx];
                } else {
                    const float av = b2f(((const u16*)Res)[idx]);
                    ((u16*)Cout)[idx] = f2b((av / (1.f + __expf(-av))) * v);
                }
            }
        }
    }
}

// ---- GEMM variant: 128x64 tile for N=1024 shapes (512 blocks -> 2 blocks/CU),
// same 2x BK=32 unroll ----
template <int EPI>
__global__ __launch_bounds__(256) void gemm_bt64(const u16* __restrict__ A,
                                                 const u16* __restrict__ Bt,
                                                 void* __restrict__ Cout,
                                                 const float* __restrict__ Res,
                                                 int N, int K) {
    __shared__ __attribute__((aligned(16))) u16 As[2][128 * 32];  // 16 KB
    __shared__ __attribute__((aligned(16))) u16 Bs[2][64 * 32];   // 8 KB
    const int tid = threadIdx.x;
    const int w = tid >> 6, lane = tid & 63;
    const int quad = lane >> 4, t = lane & 15;
    const int m0 = blockIdx.y * 128, n0 = blockIdx.x * 64;
    const int wm = (w >> 1) * 64, wn = (w & 1) * 32;

    const int srow = w * 16 + (lane >> 2);
    const int scol = (lane & 3) * 8;
    const u16* pA0 = A + (size_t)(m0 + srow) * K + scol;
    const u16* pA1 = pA0 + (size_t)64 * K;
    const u16* pB0 = Bt + (size_t)(n0 + srow) * K + scol;

    f32x4 acc[4][2];
    #pragma unroll
    for (int i = 0; i < 4; ++i)
        #pragma unroll
        for (int j = 0; j < 2; ++j) acc[i][j] = (f32x4){0.f, 0.f, 0.f, 0.f};

    for (int kb = 0; kb < K; kb += 64) {
        __syncthreads();
        stage16(pA0 + kb,      (char*)As[0] + w * 1024);
        stage16(pA1 + kb,      (char*)As[0] + 4096 + w * 1024);
        stage16(pB0 + kb,      (char*)Bs[0] + w * 1024);
        stage16(pA0 + kb + 32, (char*)As[1] + w * 1024);
        stage16(pA1 + kb + 32, (char*)As[1] + 4096 + w * 1024);
        stage16(pB0 + kb + 32, (char*)Bs[1] + w * 1024);
        __syncthreads();
        #pragma unroll
        for (int hf = 0; hf < 2; ++hf) {
            bf16x8 af[4], bfr[2];
            #pragma unroll
            for (int mi = 0; mi < 4; ++mi)
                af[mi] = *(const bf16x8*)((char*)As[hf] + (wm + mi * 16 + t) * 64 + quad * 16);
            #pragma unroll
            for (int ni = 0; ni < 2; ++ni)
                bfr[ni] = *(const bf16x8*)((char*)Bs[hf] + (wn + ni * 16 + t) * 64 + quad * 16);
            #pragma unroll
            for (int mi = 0; mi < 4; ++mi)
                #pragma unroll
                for (int ni = 0; ni < 2; ++ni)
                    acc[mi][ni] = __builtin_amdgcn_mfma_f32_16x16x32_bf16(af[mi], bfr[ni],
                                                                         acc[mi][ni], 0, 0, 0);
        }
    }
    #pragma unroll
    for (int mi = 0; mi < 4; ++mi) {
        const int row0 = m0 + wm + mi * 16 + quad * 4;
        #pragma unroll
        for (int ni = 0; ni < 2; ++ni) {
            const int col = n0 + wn + ni * 16 + t;
            #pragma unroll
            for (int r = 0; r < 4; ++r) {
                const size_t idx = (size_t)(row0 + r) * N + col;
                const float v = acc[mi][ni][r];
                if (EPI == 0) ((u16*)Cout)[idx]   = f2b(v);
                else          ((float*)Cout)[idx] = v + Res[idx];
            }
        }
    }
}

// ---- flash attention: qkv (4096 x 3072 bf16, roped), y (4096 x 1024 bf16) ----
// R4 inner structure (K staged in LDS, single V buffer, 2 barriers/iter) wrapped in
// CAUSAL PAIR BALANCING: block pairk handles q-tiles (31-pairk) then (pairk) ->
// every block does exactly 33 K-tiles; 512 uniform blocks = 2/CU, no tail.
// DPP softmax; diagonal-only mask; folded Q-scale.
// Vts XOR-swizzled: V[key][d] at row d, block (key>>3)^(d>>3), elem key&7.
__global__ __launch_bounds__(256) void attn_kernel(const u16* __restrict__ qkv,
                                                   const int* __restrict__ ymask,
                                                   u16* __restrict__ y) {
    const int pairk = blockIdx.x;            // 0..15
    const int h = blockIdx.y, b = blockIdx.z;
    const int tid = threadIdx.x;
    const int w = tid >> 6, lane = tid & 63;
    const int quad = lane >> 4, t = lane & 15;

    __shared__ __attribute__((aligned(16))) u16 Ks[64 * 72];    // [key][d], 144B rows
    __shared__ __attribute__((aligned(16))) u16 Vts[64 * 72];   // [d][key], swizzled
    __shared__ __attribute__((aligned(16))) u16 Ps[4][16 * 72]; // per-wave P [m][key]
    __shared__ int ymL[64];
    if (pairk == 0 && tid < 64) ymL[tid] = ymask[b * 64 + tid];

    // staging assignment: thread -> (key = tid>>3 and +32, dg = tid&7)
    const int skey = tid >> 3, sdg = tid & 7;
    const u16* pK = qkv + (size_t)(b * 2048 + skey) * 3072 + h * 64 + sdg * 8 + 1024;
    const int sblk0 = (skey >> 3) ^ sdg;          // Vts block for keys 0..31 set
    const int sblk1 = (4 + (skey >> 3)) ^ sdg;    // keys 32..63 set

    for (int seg = 0; seg < 2; ++seg) {
        const int qt = seg ? pairk : 31 - pairk;  // long segment first
        const int q0 = qt * 64;

        bf16x8 aQ[2];
        {
            const u16* qp = qkv + (size_t)(b * 2048 + q0 + w * 16 + t) * 3072 + h * 64 + quad * 8;
            aQ[0] = *(const bf16x8*)qp;
            aQ[1] = *(const bf16x8*)(qp + 32);
            #pragma unroll
            for (int i = 0; i < 8; ++i) {   // fold 1/sqrt(64): *2^-3 exact in bf16
                aQ[0][i] = (short)f2b(b2f((u16)aQ[0][i]) * 0.125f);
                aQ[1][i] = (short)f2b(b2f((u16)aQ[1][i]) * 0.125f);
            }
        }

        f32x4 accO[4] = {(f32x4){0,0,0,0},(f32x4){0,0,0,0},(f32x4){0,0,0,0},(f32x4){0,0,0,0}};
        float mOld[4] = {-INFINITY, -INFINITY, -INFINITY, -INFINITY};
        float lSum[4] = {0.f, 0.f, 0.f, 0.f};

        for (int kb = 0; kb <= qt; ++kb) {
            // global loads issued before the barrier (latency overlaps drain)
            const u16* pk = pK + (size_t)kb * 196608;        // kb*64*3072
            const uint4 kv0 = *(const uint4*)pk;
            const uint4 vv0 = *(const uint4*)(pk + 1024);
            const uint4 kv1 = *(const uint4*)(pk + 98304);   // +32*3072
            const uint4 vv1 = *(const uint4*)(pk + 99328);
            __syncthreads();                 // prior iteration's LDS reads done
            *(uint4*)((char*)Ks + skey * 144 + sdg * 16) = kv0;
            *(uint4*)((char*)Ks + (skey + 32) * 144 + sdg * 16) = kv1;
            {
                const u16* vp0 = (const u16*)&vv0;
                const u16* vp1 = (const u16*)&vv1;
                #pragma unroll
                for (int jj = 0; jj < 8; ++jj) {
                    const int row = sdg * 8 + jj;
                    Vts[row * 72 + sblk0 * 8 + (skey & 7)] = vp0[jj];
                    Vts[row * 72 + sblk1 * 8 + (skey & 7)] = vp1[jj];
                }
            }
            __syncthreads();

            float s[4][4];
            __builtin_amdgcn_s_setprio(1);
            #pragma unroll
            for (int ni = 0; ni < 4; ++ni) {
                bf16x8 bK0 = *(const bf16x8*)((char*)Ks + (ni * 16 + t) * 144 + quad * 16);
                bf16x8 bK1 = *(const bf16x8*)((char*)Ks + (ni * 16 + t) * 144 + 64 + quad * 16);
                f32x4 sa = (f32x4){0.f, 0.f, 0.f, 0.f};
                sa = __builtin_amdgcn_mfma_f32_16x16x32_bf16(aQ[0], bK0, sa, 0, 0, 0);
                sa = __builtin_amdgcn_mfma_f32_16x16x32_bf16(aQ[1], bK1, sa, 0, 0, 0);
                #pragma unroll
                for (int r = 0; r < 4; ++r) s[ni][r] = sa[r];
            }
            __builtin_amdgcn_s_setprio(0);

            // mask only on the diagonal tile; ym text-mask only in the qt==0 tile.
            if (kb == qt) {
                const int irow = q0 + w * 16 + quad * 4;
                #pragma unroll
                for (int ni = 0; ni < 4; ++ni)
                    #pragma unroll
                    for (int r = 0; r < 4; ++r) {
                        const int i = irow + r, j = kb * 64 + ni * 16 + t;
                        const bool ok = (j <= i) || (qt == 0 && ymL[i & 63] && ymL[j & 63]);
                        if (!ok) s[ni][r] = -INFINITY;
                    }
            }

            float alpha[4];
            bool upd = false;
            #pragma unroll
            for (int r = 0; r < 4; ++r) {
                float mt = fmaxf(fmaxf(s[0][r], s[1][r]), fmaxf(s[2][r], s[3][r]));
                mt = rowmax16(mt);                       // DPP, VALU-rate
                const float mNew = fmaxf(mOld[r], mt);
                upd = upd || (mNew > mOld[r]);
                alpha[r] = __expf(mOld[r] - mNew);
                #pragma unroll
                for (int ni = 0; ni < 4; ++ni) s[ni][r] = __expf(s[ni][r] - mNew);
                mOld[r] = mNew;
            }

            // P (C-layout) -> per-wave LDS, issued early; ds_write latency hides
            // under the DPP sum-reduces below. Same-wave, no barrier needed.
            u16* Pw = Ps[w];
            #pragma unroll
            for (int ni = 0; ni < 4; ++ni)
                #pragma unroll
                for (int r = 0; r < 4; ++r)
                    Pw[(quad * 4 + r) * 72 + ni * 16 + t] = f2b(s[ni][r]);

            #pragma unroll
            for (int r = 0; r < 4; ++r) {
                float rs = (s[0][r] + s[1][r]) + (s[2][r] + s[3][r]);
                rs = rowsum16(rs);                       // DPP, VALU-rate
                lSum[r] = lSum[r] * alpha[r] + rs;
            }
            if (__any(upd)) {               // skip O-rescale when no row's max moved
                #pragma unroll
                for (int dt = 0; dt < 4; ++dt)
                    #pragma unroll
                    for (int r = 0; r < 4; ++r) accO[dt][r] *= alpha[r];
            }

            bf16x8 aP0 = *(const bf16x8*)((char*)Pw + t * 144 + quad * 16);
            bf16x8 aP1 = *(const bf16x8*)((char*)Pw + t * 144 + 64 + quad * 16);
            __builtin_amdgcn_s_setprio(1);
            #pragma unroll
            for (int dt = 0; dt < 4; ++dt) {
                const int row = dt * 16 + t, rb = row >> 3;
                bf16x8 bV0 = *(const bf16x8*)((char*)Vts + row * 144 + ((quad ^ rb) << 4));
                bf16x8 bV1 = *(const bf16x8*)((char*)Vts + row * 144 + (((4 + quad) ^ rb) << 4));
                accO[dt] = __builtin_amdgcn_mfma_f32_16x16x32_bf16(aP0, bV0, accO[dt], 0, 0, 0);
                accO[dt] = __builtin_amdgcn_mfma_f32_16x16x32_bf16(aP1, bV1, accO[dt], 0, 0, 0);
            }
            __builtin_amdgcn_s_setprio(0);
        }
        const int orow = q0 + w * 16 + quad * 4;
        #pragma unroll
        for (int dt = 0; dt < 4; ++dt)
            #pragma unroll
            for (int r = 0; r < 4; ++r) {
                const size_t idx = (size_t)(b * 2048 + orow + r) * 1024 + h * 64 + dt * 16 + t;
                y[idx] = f2b(accO[dt][r] / lSum[r]);
            }
    }
}

extern "C" void kernel_launch(void* const* d_in, const int* in_sizes, int n_in,
                              void* d_out, int out_size, void* d_ws, size_t ws_size,
                              hipStream_t stream) {
    const float* x     = (const float*)d_in[0];
    const int*   ym    = (const int*)d_in[1];
    const float* Wqkv  = (const float*)d_in[2];
    const float* Wattn = (const float*)d_in[3];
    const float* s1    = (const float*)d_in[4];
    const float* s2    = (const float*)d_in[5];
    const float* Wfc1  = (const float*)d_in[6];
    const float* Wfc2  = (const float*)d_in[7];
    const float* Wmlp  = (const float*)d_in[8];

    char* ws = (char*)d_ws;
    u16*   h    = (u16*)(ws + 0);          // 8 MB bf16; reused as attention output
    u16*   qkv  = (u16*)(ws + 8388608);    // 24 MB bf16; later reused as fc1/m
    u16*   fc1  = qkv;
    float* xr   = (float*)(ws + 33554432); // 16 MB fp32 residual
    u16*   WtA  = (u16*)(ws + 50331648);   // 2 MB
    u16*   WtF1 = (u16*)(ws + 52428800);   // 5.5 MB
    u16*   WtF2 = (u16*)(ws + 58195968);   // 5.5 MB
    u16*   WtM  = (u16*)(ws + 63963136);   // 5.5 MB
    u16*   WtQ  = (u16*)(ws + 73400320);   // 6 MB
    const dim3 tb(32, 8);

    transpose_all<<<12544, tb, 0, stream>>>(Wqkv, Wattn, Wfc1, Wfc2, Wmlp,
                                            WtQ, WtA, WtF1, WtF2, WtM);
    rmsnorm_f32<<<4096, 256, 0, stream>>>(x, s1, h);
    gemm_bt<0><<<dim3(24, 32), 256, 0, stream>>>(h, WtQ, qkv, nullptr, 3072, 1024);
    rope_kernel<<<512, 256, 0, stream>>>(qkv);
    attn_kernel<<<dim3(16, 16, 2), 256, 0, stream>>>(qkv, ym, h);   // h dead -> y
    gemm_bt64<1><<<dim3(16, 32), 256, 0, stream>>>(h, WtA, xr, x, 1024, 1024);
    rmsnorm_f32<<<4096, 256, 0, stream>>>(xr, s2, h);
    gemm_bt<0><<<dim3(22, 32), 256, 0, stream>>>(h, WtF1, fc1, nullptr, 2816, 1024);
    gemm_bt<2><<<dim3(22, 32), 256, 0, stream>>>(h, WtF2, fc1, fc1, 2816, 1024);
    gemm_bt64<1><<<dim3(16, 32), 256, 0, stream>>>(fc1, WtM, (float*)d_out, xr, 1024, 2816);
}

// Round 7
// 370.107 us; speedup vs baseline: 1.2253x; 1.0056x over previous
//
#include <hip/hip_runtime.h>
#include <stdint.h>

typedef unsigned short u16;
typedef __attribute__((ext_vector_type(8))) short bf16x8;
typedef __attribute__((ext_vector_type(4))) float f32x4;

__device__ __forceinline__ float b2f(u16 u) {
    union { float f; uint32_t u; } v; v.u = ((uint32_t)u) << 16; return v.f;
}
__device__ __forceinline__ u16 f2b(float f) {
    union { float f; uint32_t u; } v; v.f = f;
    uint32_t r = v.u + 0x7FFFu + ((v.u >> 16) & 1u);
    return (u16)(r >> 16);
}

// DPP cross-lane move within 16-lane rows (row_ror:N = 0x120+N). Full-rate VALU.
template <int CTRL>
__device__ __forceinline__ float dppf(float x) {
    union { float f; int i; } u; u.f = x;
    u.i = __builtin_amdgcn_update_dpp(0, u.i, CTRL, 0xF, 0xF, false);
    return u.f;
}
// all-lanes max/sum over each 16-lane DPP row via rotate-reduce
__device__ __forceinline__ float rowmax16(float v) {
    v = fmaxf(v, dppf<0x121>(v));   // ror 1
    v = fmaxf(v, dppf<0x122>(v));   // ror 2
    v = fmaxf(v, dppf<0x124>(v));   // ror 4
    v = fmaxf(v, dppf<0x128>(v));   // ror 8
    return v;
}
__device__ __forceinline__ float rowsum16(float v) {
    v += dppf<0x121>(v);
    v += dppf<0x122>(v);
    v += dppf<0x124>(v);
    v += dppf<0x128>(v);
    return v;
}

// async global->LDS, 16B/lane. LDS dest must be wave-uniform; HW adds lane*16.
__device__ __forceinline__ void stage16(const void* g, void* l) {
    __builtin_amdgcn_global_load_lds(
        (const __attribute__((address_space(1))) uint32_t*)(uintptr_t)g,
        (__attribute__((address_space(3))) uint32_t*)(uint32_t)(uintptr_t)l,
        16, 0, 0);
}

// ---- all 5 weight transposes in ONE launch: in (R x C) f32 -> out (C x R) bf16 ----
__global__ __launch_bounds__(256) void transpose_all(const float* __restrict__ Wqkv,
                                                     const float* __restrict__ Wattn,
                                                     const float* __restrict__ Wfc1,
                                                     const float* __restrict__ Wfc2,
                                                     const float* __restrict__ Wmlp,
                                                     u16* WtQ, u16* WtA, u16* WtF1,
                                                     u16* WtF2, u16* WtM) {
    __shared__ u16 tile[32][33];
    int id = blockIdx.x;
    const float* src; u16* dst; int R, C;
    if (id < 3072)      {             src = Wqkv;  dst = WtQ;  R = 1024; C = 3072; }
    else if (id < 4096) { id -= 3072; src = Wattn; dst = WtA;  R = 1024; C = 1024; }
    else if (id < 6912) { id -= 4096; src = Wfc1;  dst = WtF1; R = 1024; C = 2816; }
    else if (id < 9728) { id -= 6912; src = Wfc2;  dst = WtF2; R = 1024; C = 2816; }
    else                { id -= 9728; src = Wmlp;  dst = WtM;  R = 2816; C = 1024; }
    const int nbx = C >> 5;
    const int bx = id % nbx, by = id / nbx;
    const int cx = bx * 32, ry = by * 32;
    const int tx = threadIdx.x, ty = threadIdx.y; // 32 x 8
    #pragma unroll
    for (int i = 0; i < 32; i += 8)
        tile[ty + i][tx] = f2b(src[(size_t)(ry + ty + i) * C + cx + tx]);
    __syncthreads();
    #pragma unroll
    for (int i = 0; i < 32; i += 8)
        dst[(size_t)(cx + ty + i) * R + ry + tx] = tile[tx][ty + i];
}

// ---- rmsnorm (row = 1024): fp32 in, fp32 scale, bf16 out ----
__global__ __launch_bounds__(256) void rmsnorm_f32(const float* __restrict__ xin,
                                                   const float* __restrict__ scale,
                                                   u16* __restrict__ out) {
    const int row = blockIdx.x, tid = threadIdx.x;
    const float4 v = ((const float4*)(xin + (size_t)row * 1024))[tid];
    float ss = v.x * v.x + v.y * v.y + v.z * v.z + v.w * v.w;
    #pragma unroll
    for (int d = 32; d; d >>= 1) ss += __shfl_xor(ss, d);
    __shared__ float wsum[4];
    if ((tid & 63) == 0) wsum[tid >> 6] = ss;
    __syncthreads();
    const float r = rsqrtf((wsum[0] + wsum[1] + wsum[2] + wsum[3]) * (1.f / 1024.f) + 1e-5f);
    const float4 sc = ((const float4*)scale)[tid];
    uint2 o;
    o.x = (uint32_t)f2b(v.x * sc.x * r) | ((uint32_t)f2b(v.y * sc.y * r) << 16);
    o.y = (uint32_t)f2b(v.z * sc.z * r) | ((uint32_t)f2b(v.w * sc.w * r) << 16);
    ((uint2*)(out + (size_t)row * 1024))[tid] = o;
}

// ---- RoPE in place on q,k thirds of qkv (4096 x 3072 bf16) ----
// One thread per (row, i): trig computed ONCE, applied to 16 q-heads + 16 k-heads
// via coalesced u32 accesses (lanes 0..31 span i -> 128B contiguous per head).
__global__ __launch_bounds__(256) void rope_kernel(u16* __restrict__ qkv) {
    const int gid = blockIdx.x * 256 + threadIdx.x;  // 131072 = 4096 rows * 32 i
    const int i = gid & 31;
    const int row = gid >> 5;
    const int tpos = row & 2047;
    const float theta = expf(-(float)i * (9.210340371976184f / 32.0f));
    const float ang = (float)tpos * theta;
    const float c = cosf(ang), s = sinf(ang);
    uint32_t* p = (uint32_t*)qkv + (size_t)row * 1536 + i;
    #pragma unroll
    for (int h = 0; h < 16; ++h) {
        const uint32_t uq = p[h * 32];
        {
            const float xe = b2f((u16)(uq & 0xffff)), xo = b2f((u16)(uq >> 16));
            p[h * 32] = (uint32_t)f2b(xe * c - xo * s) |
                        ((uint32_t)f2b(xe * s + xo * c) << 16);
        }
        const uint32_t uk = p[512 + h * 32];
        {
            const float xe = b2f((u16)(uk & 0xffff)), xo = b2f((u16)(uk >> 16));
            p[512 + h * 32] = (uint32_t)f2b(xe * c - xo * s) |
                              ((uint32_t)f2b(xe * s + xo * c) << 16);
        }
    }
}

// ---- GEMM: A (M x K) bf16, Bt (N x K) bf16, 128x128 tile, 2x BK=32 halves per
// barrier pair (8 stage16 in flight, 32 MFMA per drain -> half the barrier stalls).
// EPI 0: Cbf16 = f2b(acc);  EPI 1: Cf32 = acc + Res_f32;  EPI 2: Cbf16 = silu(Res_bf16)*acc
template <int EPI>
__global__ __launch_bounds__(256) void gemm_bt(const u16* __restrict__ A,
                                               const u16* __restrict__ Bt,
                                               void* __restrict__ Cout,
                                               const void* __restrict__ Res,
                                               int N, int K) {
    __shared__ __attribute__((aligned(16))) u16 As[2][128 * 32];
    __shared__ __attribute__((aligned(16))) u16 Bs[2][128 * 32];
    const int tid = threadIdx.x;
    const int w = tid >> 6, lane = tid & 63;
    const int quad = lane >> 4, t = lane & 15;
    const int m0 = blockIdx.y * 128, n0 = blockIdx.x * 128;
    const int wm = (w >> 1) * 64, wn = (w & 1) * 64;

    const int srow = w * 16 + (lane >> 2);
    const int scol = (lane & 3) * 8;
    const u16* pA0 = A + (size_t)(m0 + srow) * K + scol;
    const u16* pA1 = pA0 + (size_t)64 * K;
    const u16* pB0 = Bt + (size_t)(n0 + srow) * K + scol;
    const u16* pB1 = pB0 + (size_t)64 * K;

    f32x4 acc[4][4];
    #pragma unroll
    for (int i = 0; i < 4; ++i)
        #pragma unroll
        for (int j = 0; j < 4; ++j) acc[i][j] = (f32x4){0.f, 0.f, 0.f, 0.f};

    for (int kb = 0; kb < K; kb += 64) {
        __syncthreads();                 // prior iteration's LDS reads complete
        stage16(pA0 + kb,      (char*)As[0] + w * 1024);
        stage16(pA1 + kb,      (char*)As[0] + 4096 + w * 1024);
        stage16(pB0 + kb,      (char*)Bs[0] + w * 1024);
        stage16(pB1 + kb,      (char*)Bs[0] + 4096 + w * 1024);
        stage16(pA0 + kb + 32, (char*)As[1] + w * 1024);
        stage16(pA1 + kb + 32, (char*)As[1] + 4096 + w * 1024);
        stage16(pB0 + kb + 32, (char*)Bs[1] + w * 1024);
        stage16(pB1 + kb + 32, (char*)Bs[1] + 4096 + w * 1024);
        __syncthreads();                 // vmcnt(0) drain: staging visible
        #pragma unroll
        for (int hf = 0; hf < 2; ++hf) {
            bf16x8 af[4], bfr[4];
            #pragma unroll
            for (int mi = 0; mi < 4; ++mi)
                af[mi] = *(const bf16x8*)((char*)As[hf] + (wm + mi * 16 + t) * 64 + quad * 16);
            #pragma unroll
            for (int ni = 0; ni < 4; ++ni)
                bfr[ni] = *(const bf16x8*)((char*)Bs[hf] + (wn + ni * 16 + t) * 64 + quad * 16);
            #pragma unroll
            for (int mi = 0; mi < 4; ++mi)
                #pragma unroll
                for (int ni = 0; ni < 4; ++ni)
                    acc[mi][ni] = __builtin_amdgcn_mfma_f32_16x16x32_bf16(af[mi], bfr[ni],
                                                                         acc[mi][ni], 0, 0, 0);
        }
    }
    #pragma unroll
    for (int mi = 0; mi < 4; ++mi) {
        const int row0 = m0 + wm + mi * 16 + quad * 4;
        #pragma unroll
        for (int ni = 0; ni < 4; ++ni) {
            const int col = n0 + wn + ni * 16 + t;
            #pragma unroll
            for (int r = 0; r < 4; ++r) {
                const size_t idx = (size_t)(row0 + r) * N + col;
                const float v = acc[mi][ni][r];
                if (EPI == 0) {
                    ((u16*)Cout)[idx] = f2b(v);
                } else if (EPI == 1) {
                    ((float*)Cout)[idx] = v + ((const float*)Res)[idx];
                } else {
                    const float av = b2f(((const u16*)Res)[idx]);
                    ((u16*)Cout)[idx] = f2b((av / (1.f + __expf(-av))) * v);
                }
            }
        }
    }
}

// ---- GEMM variant: 128x64 tile for N=1024 shapes (512 blocks -> 2 blocks/CU),
// same 2x BK=32 unroll ----
template <int EPI>
__global__ __launch_bounds__(256) void gemm_bt64(const u16* __restrict__ A,
                                                 const u16* __restrict__ Bt,
                                                 void* __restrict__ Cout,
                                                 const float* __restrict__ Res,
                                                 int N, int K) {
    __shared__ __attribute__((aligned(16))) u16 As[2][128 * 32];  // 16 KB
    __shared__ __attribute__((aligned(16))) u16 Bs[2][64 * 32];   // 8 KB
    const int tid = threadIdx.x;
    const int w = tid >> 6, lane = tid & 63;
    const int quad = lane >> 4, t = lane & 15;
    const int m0 = blockIdx.y * 128, n0 = blockIdx.x * 64;
    const int wm = (w >> 1) * 64, wn = (w & 1) * 32;

    const int srow = w * 16 + (lane >> 2);
    const int scol = (lane & 3) * 8;
    const u16* pA0 = A + (size_t)(m0 + srow) * K + scol;
    const u16* pA1 = pA0 + (size_t)64 * K;
    const u16* pB0 = Bt + (size_t)(n0 + srow) * K + scol;

    f32x4 acc[4][2];
    #pragma unroll
    for (int i = 0; i < 4; ++i)
        #pragma unroll
        for (int j = 0; j < 2; ++j) acc[i][j] = (f32x4){0.f, 0.f, 0.f, 0.f};

    for (int kb = 0; kb < K; kb += 64) {
        __syncthreads();
        stage16(pA0 + kb,      (char*)As[0] + w * 1024);
        stage16(pA1 + kb,      (char*)As[0] + 4096 + w * 1024);
        stage16(pB0 + kb,      (char*)Bs[0] + w * 1024);
        stage16(pA0 + kb + 32, (char*)As[1] + w * 1024);
        stage16(pA1 + kb + 32, (char*)As[1] + 4096 + w * 1024);
        stage16(pB0 + kb + 32, (char*)Bs[1] + w * 1024);
        __syncthreads();
        #pragma unroll
        for (int hf = 0; hf < 2; ++hf) {
            bf16x8 af[4], bfr[2];
            #pragma unroll
            for (int mi = 0; mi < 4; ++mi)
                af[mi] = *(const bf16x8*)((char*)As[hf] + (wm + mi * 16 + t) * 64 + quad * 16);
            #pragma unroll
            for (int ni = 0; ni < 2; ++ni)
                bfr[ni] = *(const bf16x8*)((char*)Bs[hf] + (wn + ni * 16 + t) * 64 + quad * 16);
            #pragma unroll
            for (int mi = 0; mi < 4; ++mi)
                #pragma unroll
                for (int ni = 0; ni < 2; ++ni)
                    acc[mi][ni] = __builtin_amdgcn_mfma_f32_16x16x32_bf16(af[mi], bfr[ni],
                                                                         acc[mi][ni], 0, 0, 0);
        }
    }
    #pragma unroll
    for (int mi = 0; mi < 4; ++mi) {
        const int row0 = m0 + wm + mi * 16 + quad * 4;
        #pragma unroll
        for (int ni = 0; ni < 2; ++ni) {
            const int col = n0 + wn + ni * 16 + t;
            #pragma unroll
            for (int r = 0; r < 4; ++r) {
                const size_t idx = (size_t)(row0 + r) * N + col;
                const float v = acc[mi][ni][r];
                if (EPI == 0) ((u16*)Cout)[idx]   = f2b(v);
                else          ((float*)Cout)[idx] = v + Res[idx];
            }
        }
    }
}

// ---- flash attention: qkv (4096 x 3072 bf16, roped), y (4096 x 1024 bf16) ----
// R6 structure (pair-balanced: block does q-tiles (31-pairk) then (pairk) = 33
// uniform K-tiles) + XCD-GROUPED block mapping: all 16 blocks of one (h,b) land
// on ONE XCD (assuming round-robin linear-id -> XCD), so each XCD's L2 holds its
// 4 groups' K/V (4 x 1 MB = L2-resident) -> K/V tile reads become L2 hits.
// gid = xcd + 8*(slot*16 + pairk), group = slot*8 + xcd, h = group&15, b = group>>4.
// DPP softmax; diagonal-only mask; folded Q-scale; Vts XOR-swizzled.
__global__ __launch_bounds__(256) void attn_kernel(const u16* __restrict__ qkv,
                                                   const int* __restrict__ ymask,
                                                   u16* __restrict__ y) {
    const int gid = blockIdx.x;              // 0..511
    const int xcd = gid & 7;
    const int j2 = gid >> 3;                 // 0..63
    const int slot = j2 >> 4;                // 0..3
    const int pairk = j2 & 15;               // 0..15
    const int group = slot * 8 + xcd;        // 0..31
    const int h = group & 15, b = group >> 4;
    const int tid = threadIdx.x;
    const int w = tid >> 6, lane = tid & 63;
    const int quad = lane >> 4, t = lane & 15;

    __shared__ __attribute__((aligned(16))) u16 Ks[64 * 72];    // [key][d], 144B rows
    __shared__ __attribute__((aligned(16))) u16 Vts[64 * 72];   // [d][key], swizzled
    __shared__ __attribute__((aligned(16))) u16 Ps[4][16 * 72]; // per-wave P [m][key]
    __shared__ int ymL[64];
    if (pairk == 0 && tid < 64) ymL[tid] = ymask[b * 64 + tid];

    // staging assignment: thread -> (key = tid>>3 and +32, dg = tid&7)
    const int skey = tid >> 3, sdg = tid & 7;
    const u16* pK = qkv + (size_t)(b * 2048 + skey) * 3072 + h * 64 + sdg * 8 + 1024;
    const int sblk0 = (skey >> 3) ^ sdg;          // Vts block for keys 0..31 set
    const int sblk1 = (4 + (skey >> 3)) ^ sdg;    // keys 32..63 set

    for (int seg = 0; seg < 2; ++seg) {
        const int qt = seg ? pairk : 31 - pairk;  // long segment first
        const int q0 = qt * 64;

        bf16x8 aQ[2];
        {
            const u16* qp = qkv + (size_t)(b * 2048 + q0 + w * 16 + t) * 3072 + h * 64 + quad * 8;
            aQ[0] = *(const bf16x8*)qp;
            aQ[1] = *(const bf16x8*)(qp + 32);
            #pragma unroll
            for (int i = 0; i < 8; ++i) {   // fold 1/sqrt(64): *2^-3 exact in bf16
                aQ[0][i] = (short)f2b(b2f((u16)aQ[0][i]) * 0.125f);
                aQ[1][i] = (short)f2b(b2f((u16)aQ[1][i]) * 0.125f);
            }
        }

        f32x4 accO[4] = {(f32x4){0,0,0,0},(f32x4){0,0,0,0},(f32x4){0,0,0,0},(f32x4){0,0,0,0}};
        float mOld[4] = {-INFINITY, -INFINITY, -INFINITY, -INFINITY};
        float lSum[4] = {0.f, 0.f, 0.f, 0.f};

        for (int kb = 0; kb <= qt; ++kb) {
            // global loads issued before the barrier (latency overlaps drain)
            const u16* pk = pK + (size_t)kb * 196608;        // kb*64*3072
            const uint4 kv0 = *(const uint4*)pk;
            const uint4 vv0 = *(const uint4*)(pk + 1024);
            const uint4 kv1 = *(const uint4*)(pk + 98304);   // +32*3072
            const uint4 vv1 = *(const uint4*)(pk + 99328);
            __syncthreads();                 // prior iteration's LDS reads done
            *(uint4*)((char*)Ks + skey * 144 + sdg * 16) = kv0;
            *(uint4*)((char*)Ks + (skey + 32) * 144 + sdg * 16) = kv1;
            {
                const u16* vp0 = (const u16*)&vv0;
                const u16* vp1 = (const u16*)&vv1;
                #pragma unroll
                for (int jj = 0; jj < 8; ++jj) {
                    const int row = sdg * 8 + jj;
                    Vts[row * 72 + sblk0 * 8 + (skey & 7)] = vp0[jj];
                    Vts[row * 72 + sblk1 * 8 + (skey & 7)] = vp1[jj];
                }
            }
            __syncthreads();

            float s[4][4];
            __builtin_amdgcn_s_setprio(1);
            #pragma unroll
            for (int ni = 0; ni < 4; ++ni) {
                bf16x8 bK0 = *(const bf16x8*)((char*)Ks + (ni * 16 + t) * 144 + quad * 16);
                bf16x8 bK1 = *(const bf16x8*)((char*)Ks + (ni * 16 + t) * 144 + 64 + quad * 16);
                f32x4 sa = (f32x4){0.f, 0.f, 0.f, 0.f};
                sa = __builtin_amdgcn_mfma_f32_16x16x32_bf16(aQ[0], bK0, sa, 0, 0, 0);
                sa = __builtin_amdgcn_mfma_f32_16x16x32_bf16(aQ[1], bK1, sa, 0, 0, 0);
                #pragma unroll
                for (int r = 0; r < 4; ++r) s[ni][r] = sa[r];
            }
            __builtin_amdgcn_s_setprio(0);

            // mask only on the diagonal tile; ym text-mask only in the qt==0 tile.
            if (kb == qt) {
                const int irow = q0 + w * 16 + quad * 4;
                #pragma unroll
                for (int ni = 0; ni < 4; ++ni)
                    #pragma unroll
                    for (int r = 0; r < 4; ++r) {
                        const int i = irow + r, j = kb * 64 + ni * 16 + t;
                        const bool ok = (j <= i) || (qt == 0 && ymL[i & 63] && ymL[j & 63]);
                        if (!ok) s[ni][r] = -INFINITY;
                    }
            }

            float alpha[4];
            bool upd = false;
            #pragma unroll
            for (int r = 0; r < 4; ++r) {
                float mt = fmaxf(fmaxf(s[0][r], s[1][r]), fmaxf(s[2][r], s[3][r]));
                mt = rowmax16(mt);                       // DPP, VALU-rate
                const float mNew = fmaxf(mOld[r], mt);
                upd = upd || (mNew > mOld[r]);
                alpha[r] = __expf(mOld[r] - mNew);
                #pragma unroll
                for (int ni = 0; ni < 4; ++ni) s[ni][r] = __expf(s[ni][r] - mNew);
                mOld[r] = mNew;
            }

            // P (C-layout) -> per-wave LDS, issued early; ds_write latency hides
            // under the DPP sum-reduces below. Same-wave, no barrier needed.
            u16* Pw = Ps[w];
            #pragma unroll
            for (int ni = 0; ni < 4; ++ni)
                #pragma unroll
                for (int r = 0; r < 4; ++r)
                    Pw[(quad * 4 + r) * 72 + ni * 16 + t] = f2b(s[ni][r]);

            #pragma unroll
            for (int r = 0; r < 4; ++r) {
                float rs = (s[0][r] + s[1][r]) + (s[2][r] + s[3][r]);
                rs = rowsum16(rs);                       // DPP, VALU-rate
                lSum[r] = lSum[r] * alpha[r] + rs;
            }
            if (__any(upd)) {               // skip O-rescale when no row's max moved
                #pragma unroll
                for (int dt = 0; dt < 4; ++dt)
                    #pragma unroll
                    for (int r = 0; r < 4; ++r) accO[dt][r] *= alpha[r];
            }

            bf16x8 aP0 = *(const bf16x8*)((char*)Pw + t * 144 + quad * 16);
            bf16x8 aP1 = *(const bf16x8*)((char*)Pw + t * 144 + 64 + quad * 16);
            __builtin_amdgcn_s_setprio(1);
            #pragma unroll
            for (int dt = 0; dt < 4; ++dt) {
                const int row = dt * 16 + t, rb = row >> 3;
                bf16x8 bV0 = *(const bf16x8*)((char*)Vts + row * 144 + ((quad ^ rb) << 4));
                bf16x8 bV1 = *(const bf16x8*)((char*)Vts + row * 144 + (((4 + quad) ^ rb) << 4));
                accO[dt] = __builtin_amdgcn_mfma_f32_16x16x32_bf16(aP0, bV0, accO[dt], 0, 0, 0);
                accO[dt] = __builtin_amdgcn_mfma_f32_16x16x32_bf16(aP1, bV1, accO[dt], 0, 0, 0);
            }
            __builtin_amdgcn_s_setprio(0);
        }
        const int orow = q0 + w * 16 + quad * 4;
        #pragma unroll
        for (int dt = 0; dt < 4; ++dt)
            #pragma unroll
            for (int r = 0; r < 4; ++r) {
                const size_t idx = (size_t)(b * 2048 + orow + r) * 1024 + h * 64 + dt * 16 + t;
                y[idx] = f2b(accO[dt][r] / lSum[r]);
            }
    }
}

extern "C" void kernel_launch(void* const* d_in, const int* in_sizes, int n_in,
                              void* d_out, int out_size, void* d_ws, size_t ws_size,
                              hipStream_t stream) {
    const float* x     = (const float*)d_in[0];
    const int*   ym    = (const int*)d_in[1];
    const float* Wqkv  = (const float*)d_in[2];
    const float* Wattn = (const float*)d_in[3];
    const float* s1    = (const float*)d_in[4];
    const float* s2    = (const float*)d_in[5];
    const float* Wfc1  = (const float*)d_in[6];
    const float* Wfc2  = (const float*)d_in[7];
    const float* Wmlp  = (const float*)d_in[8];

    char* ws = (char*)d_ws;
    u16*   h    = (u16*)(ws + 0);          // 8 MB bf16; reused as attention output
    u16*   qkv  = (u16*)(ws + 8388608);    // 24 MB bf16; later reused as fc1/m
    u16*   fc1  = qkv;
    float* xr   = (float*)(ws + 33554432); // 16 MB fp32 residual
    u16*   WtA  = (u16*)(ws + 50331648);   // 2 MB
    u16*   WtF1 = (u16*)(ws + 52428800);   // 5.5 MB
    u16*   WtF2 = (u16*)(ws + 58195968);   // 5.5 MB
    u16*   WtM  = (u16*)(ws + 63963136);   // 5.5 MB
    u16*   WtQ  = (u16*)(ws + 73400320);   // 6 MB
    const dim3 tb(32, 8);

    transpose_all<<<12544, tb, 0, stream>>>(Wqkv, Wattn, Wfc1, Wfc2, Wmlp,
                                            WtQ, WtA, WtF1, WtF2, WtM);
    rmsnorm_f32<<<4096, 256, 0, stream>>>(x, s1, h);
    gemm_bt<0><<<dim3(24, 32), 256, 0, stream>>>(h, WtQ, qkv, nullptr, 3072, 1024);
    rope_kernel<<<512, 256, 0, stream>>>(qkv);
    attn_kernel<<<512, 256, 0, stream>>>(qkv, ym, h);   // h dead -> y
    gemm_bt64<1><<<dim3(16, 32), 256, 0, stream>>>(h, WtA, xr, x, 1024, 1024);
    rmsnorm_f32<<<4096, 256, 0, stream>>>(xr, s2, h);
    gemm_bt<0><<<dim3(22, 32), 256, 0, stream>>>(h, WtF1, fc1, nullptr, 2816, 1024);
    gemm_bt<2><<<dim3(22, 32), 256, 0, stream>>>(h, WtF2, fc1, fc1, 2816, 1024);
    gemm_bt64<1><<<dim3(16, 32), 256, 0, stream>>>(fc1, WtM, (float*)d_out, xr, 1024, 2816);
}

// Round 8
// 351.822 us; speedup vs baseline: 1.2890x; 1.0520x over previous
//
#include <hip/hip_runtime.h>
#include <stdint.h>

typedef unsigned short u16;
typedef __attribute__((ext_vector_type(8))) short bf16x8;
typedef __attribute__((ext_vector_type(4))) float f32x4;

__device__ __forceinline__ float b2f(u16 u) {
    union { float f; uint32_t u; } v; v.u = ((uint32_t)u) << 16; return v.f;
}
__device__ __forceinline__ u16 f2b(float f) {
    union { float f; uint32_t u; } v; v.f = f;
    uint32_t r = v.u + 0x7FFFu + ((v.u >> 16) & 1u);
    return (u16)(r >> 16);
}

// DPP cross-lane move within 16-lane rows (row_ror:N = 0x120+N). Full-rate VALU.
template <int CTRL>
__device__ __forceinline__ float dppf(float x) {
    union { float f; int i; } u; u.f = x;
    u.i = __builtin_amdgcn_update_dpp(0, u.i, CTRL, 0xF, 0xF, false);
    return u.f;
}
// all-lanes max/sum over each 16-lane DPP row via rotate-reduce
__device__ __forceinline__ float rowmax16(float v) {
    v = fmaxf(v, dppf<0x121>(v));   // ror 1
    v = fmaxf(v, dppf<0x122>(v));   // ror 2
    v = fmaxf(v, dppf<0x124>(v));   // ror 4
    v = fmaxf(v, dppf<0x128>(v));   // ror 8
    return v;
}
__device__ __forceinline__ float rowsum16(float v) {
    v += dppf<0x121>(v);
    v += dppf<0x122>(v);
    v += dppf<0x124>(v);
    v += dppf<0x128>(v);
    return v;
}

// async global->LDS, 16B/lane. LDS dest must be wave-uniform; HW adds lane*16.
__device__ __forceinline__ void stage16(const void* g, void* l) {
    __builtin_amdgcn_global_load_lds(
        (const __attribute__((address_space(1))) uint32_t*)(uintptr_t)g,
        (__attribute__((address_space(3))) uint32_t*)(uint32_t)(uintptr_t)l,
        16, 0, 0);
}

// ---- all 5 weight transposes in ONE launch: in (R x C) f32 -> out (C x R) bf16 ----
__global__ __launch_bounds__(256) void transpose_all(const float* __restrict__ Wqkv,
                                                     const float* __restrict__ Wattn,
                                                     const float* __restrict__ Wfc1,
                                                     const float* __restrict__ Wfc2,
                                                     const float* __restrict__ Wmlp,
                                                     u16* WtQ, u16* WtA, u16* WtF1,
                                                     u16* WtF2, u16* WtM) {
    __shared__ u16 tile[32][33];
    int id = blockIdx.x;
    const float* src; u16* dst; int R, C;
    if (id < 3072)      {             src = Wqkv;  dst = WtQ;  R = 1024; C = 3072; }
    else if (id < 4096) { id -= 3072; src = Wattn; dst = WtA;  R = 1024; C = 1024; }
    else if (id < 6912) { id -= 4096; src = Wfc1;  dst = WtF1; R = 1024; C = 2816; }
    else if (id < 9728) { id -= 6912; src = Wfc2;  dst = WtF2; R = 1024; C = 2816; }
    else                { id -= 9728; src = Wmlp;  dst = WtM;  R = 2816; C = 1024; }
    const int nbx = C >> 5;
    const int bx = id % nbx, by = id / nbx;
    const int cx = bx * 32, ry = by * 32;
    const int tx = threadIdx.x, ty = threadIdx.y; // 32 x 8
    #pragma unroll
    for (int i = 0; i < 32; i += 8)
        tile[ty + i][tx] = f2b(src[(size_t)(ry + ty + i) * C + cx + tx]);
    __syncthreads();
    #pragma unroll
    for (int i = 0; i < 32; i += 8)
        dst[(size_t)(cx + ty + i) * R + ry + tx] = tile[tx][ty + i];
}

// ---- rmsnorm (row = 1024): fp32 in, fp32 scale, bf16 out ----
__global__ __launch_bounds__(256) void rmsnorm_f32(const float* __restrict__ xin,
                                                   const float* __restrict__ scale,
                                                   u16* __restrict__ out) {
    const int row = blockIdx.x, tid = threadIdx.x;
    const float4 v = ((const float4*)(xin + (size_t)row * 1024))[tid];
    float ss = v.x * v.x + v.y * v.y + v.z * v.z + v.w * v.w;
    #pragma unroll
    for (int d = 32; d; d >>= 1) ss += __shfl_xor(ss, d);
    __shared__ float wsum[4];
    if ((tid & 63) == 0) wsum[tid >> 6] = ss;
    __syncthreads();
    const float r = rsqrtf((wsum[0] + wsum[1] + wsum[2] + wsum[3]) * (1.f / 1024.f) + 1e-5f);
    const float4 sc = ((const float4*)scale)[tid];
    uint2 o;
    o.x = (uint32_t)f2b(v.x * sc.x * r) | ((uint32_t)f2b(v.y * sc.y * r) << 16);
    o.y = (uint32_t)f2b(v.z * sc.z * r) | ((uint32_t)f2b(v.w * sc.w * r) << 16);
    ((uint2*)(out + (size_t)row * 1024))[tid] = o;
}

// ---- RoPE in place on q,k thirds of qkv (4096 x 3072 bf16) ----
// One thread per (row, i): trig computed ONCE, applied to 16 q-heads + 16 k-heads
// via coalesced u32 accesses (lanes 0..31 span i -> 128B contiguous per head).
__global__ __launch_bounds__(256) void rope_kernel(u16* __restrict__ qkv) {
    const int gid = blockIdx.x * 256 + threadIdx.x;  // 131072 = 4096 rows * 32 i
    const int i = gid & 31;
    const int row = gid >> 5;
    const int tpos = row & 2047;
    const float theta = expf(-(float)i * (9.210340371976184f / 32.0f));
    const float ang = (float)tpos * theta;
    const float c = cosf(ang), s = sinf(ang);
    uint32_t* p = (uint32_t*)qkv + (size_t)row * 1536 + i;
    #pragma unroll
    for (int h = 0; h < 16; ++h) {
        const uint32_t uq = p[h * 32];
        {
            const float xe = b2f((u16)(uq & 0xffff)), xo = b2f((u16)(uq >> 16));
            p[h * 32] = (uint32_t)f2b(xe * c - xo * s) |
                        ((uint32_t)f2b(xe * s + xo * c) << 16);
        }
        const uint32_t uk = p[512 + h * 32];
        {
            const float xe = b2f((u16)(uk & 0xffff)), xo = b2f((u16)(uk >> 16));
            p[512 + h * 32] = (uint32_t)f2b(xe * c - xo * s) |
                              ((uint32_t)f2b(xe * s + xo * c) << 16);
        }
    }
}

// ---- GEMM: A (M x K) bf16, Bt (N x K) bf16, 128x128 tile, 2x BK=32 halves per
// barrier pair (8 stage16 in flight, 32 MFMA per drain -> half the barrier stalls).
// EPI 0: Cbf16 = f2b(acc);  EPI 1: Cf32 = acc + Res_f32
template <int EPI>
__global__ __launch_bounds__(256) void gemm_bt(const u16* __restrict__ A,
                                               const u16* __restrict__ Bt,
                                               void* __restrict__ Cout,
                                               const void* __restrict__ Res,
                                               int N, int K) {
    __shared__ __attribute__((aligned(16))) u16 As[2][128 * 32];
    __shared__ __attribute__((aligned(16))) u16 Bs[2][128 * 32];
    const int tid = threadIdx.x;
    const int w = tid >> 6, lane = tid & 63;
    const int quad = lane >> 4, t = lane & 15;
    const int m0 = blockIdx.y * 128, n0 = blockIdx.x * 128;
    const int wm = (w >> 1) * 64, wn = (w & 1) * 64;

    const int srow = w * 16 + (lane >> 2);
    const int scol = (lane & 3) * 8;
    const u16* pA0 = A + (size_t)(m0 + srow) * K + scol;
    const u16* pA1 = pA0 + (size_t)64 * K;
    const u16* pB0 = Bt + (size_t)(n0 + srow) * K + scol;
    const u16* pB1 = pB0 + (size_t)64 * K;

    f32x4 acc[4][4];
    #pragma unroll
    for (int i = 0; i < 4; ++i)
        #pragma unroll
        for (int j = 0; j < 4; ++j) acc[i][j] = (f32x4){0.f, 0.f, 0.f, 0.f};

    for (int kb = 0; kb < K; kb += 64) {
        __syncthreads();                 // prior iteration's LDS reads complete
        stage16(pA0 + kb,      (char*)As[0] + w * 1024);
        stage16(pA1 + kb,      (char*)As[0] + 4096 + w * 1024);
        stage16(pB0 + kb,      (char*)Bs[0] + w * 1024);
        stage16(pB1 + kb,      (char*)Bs[0] + 4096 + w * 1024);
        stage16(pA0 + kb + 32, (char*)As[1] + w * 1024);
        stage16(pA1 + kb + 32, (char*)As[1] + 4096 + w * 1024);
        stage16(pB0 + kb + 32, (char*)Bs[1] + w * 1024);
        stage16(pB1 + kb + 32, (char*)Bs[1] + 4096 + w * 1024);
        __syncthreads();                 // vmcnt(0) drain: staging visible
        #pragma unroll
        for (int hf = 0; hf < 2; ++hf) {
            bf16x8 af[4], bfr[4];
            #pragma unroll
            for (int mi = 0; mi < 4; ++mi)
                af[mi] = *(const bf16x8*)((char*)As[hf] + (wm + mi * 16 + t) * 64 + quad * 16);
            #pragma unroll
            for (int ni = 0; ni < 4; ++ni)
                bfr[ni] = *(const bf16x8*)((char*)Bs[hf] + (wn + ni * 16 + t) * 64 + quad * 16);
            #pragma unroll
            for (int mi = 0; mi < 4; ++mi)
                #pragma unroll
                for (int ni = 0; ni < 4; ++ni)
                    acc[mi][ni] = __builtin_amdgcn_mfma_f32_16x16x32_bf16(af[mi], bfr[ni],
                                                                         acc[mi][ni], 0, 0, 0);
        }
    }
    #pragma unroll
    for (int mi = 0; mi < 4; ++mi) {
        const int row0 = m0 + wm + mi * 16 + quad * 4;
        #pragma unroll
        for (int ni = 0; ni < 4; ++ni) {
            const int col = n0 + wn + ni * 16 + t;
            #pragma unroll
            for (int r = 0; r < 4; ++r) {
                const size_t idx = (size_t)(row0 + r) * N + col;
                const float v = acc[mi][ni][r];
                if (EPI == 0) ((u16*)Cout)[idx]   = f2b(v);
                else          ((float*)Cout)[idx] = v + ((const float*)Res)[idx];
            }
        }
    }
}

// ---- GEMM variant: 128x64 tile for N=1024 shapes (512 blocks -> 2 blocks/CU),
// same 2x BK=32 unroll ----
template <int EPI>
__global__ __launch_bounds__(256) void gemm_bt64(const u16* __restrict__ A,
                                                 const u16* __restrict__ Bt,
                                                 void* __restrict__ Cout,
                                                 const float* __restrict__ Res,
                                                 int N, int K) {
    __shared__ __attribute__((aligned(16))) u16 As[2][128 * 32];  // 16 KB
    __shared__ __attribute__((aligned(16))) u16 Bs[2][64 * 32];   // 8 KB
    const int tid = threadIdx.x;
    const int w = tid >> 6, lane = tid & 63;
    const int quad = lane >> 4, t = lane & 15;
    const int m0 = blockIdx.y * 128, n0 = blockIdx.x * 64;
    const int wm = (w >> 1) * 64, wn = (w & 1) * 32;

    const int srow = w * 16 + (lane >> 2);
    const int scol = (lane & 3) * 8;
    const u16* pA0 = A + (size_t)(m0 + srow) * K + scol;
    const u16* pA1 = pA0 + (size_t)64 * K;
    const u16* pB0 = Bt + (size_t)(n0 + srow) * K + scol;

    f32x4 acc[4][2];
    #pragma unroll
    for (int i = 0; i < 4; ++i)
        #pragma unroll
        for (int j = 0; j < 2; ++j) acc[i][j] = (f32x4){0.f, 0.f, 0.f, 0.f};

    for (int kb = 0; kb < K; kb += 64) {
        __syncthreads();
        stage16(pA0 + kb,      (char*)As[0] + w * 1024);
        stage16(pA1 + kb,      (char*)As[0] + 4096 + w * 1024);
        stage16(pB0 + kb,      (char*)Bs[0] + w * 1024);
        stage16(pA0 + kb + 32, (char*)As[1] + w * 1024);
        stage16(pA1 + kb + 32, (char*)As[1] + 4096 + w * 1024);
        stage16(pB0 + kb + 32, (char*)Bs[1] + w * 1024);
        __syncthreads();
        #pragma unroll
        for (int hf = 0; hf < 2; ++hf) {
            bf16x8 af[4], bfr[2];
            #pragma unroll
            for (int mi = 0; mi < 4; ++mi)
                af[mi] = *(const bf16x8*)((char*)As[hf] + (wm + mi * 16 + t) * 64 + quad * 16);
            #pragma unroll
            for (int ni = 0; ni < 2; ++ni)
                bfr[ni] = *(const bf16x8*)((char*)Bs[hf] + (wn + ni * 16 + t) * 64 + quad * 16);
            #pragma unroll
            for (int mi = 0; mi < 4; ++mi)
                #pragma unroll
                for (int ni = 0; ni < 2; ++ni)
                    acc[mi][ni] = __builtin_amdgcn_mfma_f32_16x16x32_bf16(af[mi], bfr[ni],
                                                                         acc[mi][ni], 0, 0, 0);
        }
    }
    #pragma unroll
    for (int mi = 0; mi < 4; ++mi) {
        const int row0 = m0 + wm + mi * 16 + quad * 4;
        #pragma unroll
        for (int ni = 0; ni < 2; ++ni) {
            const int col = n0 + wn + ni * 16 + t;
            #pragma unroll
            for (int r = 0; r < 4; ++r) {
                const size_t idx = (size_t)(row0 + r) * N + col;
                const float v = acc[mi][ni][r];
                if (EPI == 0) ((u16*)Cout)[idx]   = f2b(v);
                else          ((float*)Cout)[idx] = v + Res[idx];
            }
        }
    }
}

// ---- FUSED fc1+fc2 GEMM: A (M x K), B1t/B2t (N x K); C = silu(A@W1) * (A@W2).
// A staged ONCE for both B operands: 8 stage16 / 32 MFMA per barrier pair (vs
// 12 stages across two separate kernels), half the drains per MFMA, fc1's 46 MB
// bf16 round-trip through HBM eliminated, one dispatch instead of two.
__global__ __launch_bounds__(256) void gemm_fc(const u16* __restrict__ A,
                                               const u16* __restrict__ B1t,
                                               const u16* __restrict__ B2t,
                                               u16* __restrict__ Cout,
                                               int N, int K) {
    __shared__ __attribute__((aligned(16))) u16 As[2][128 * 32];   // 16 KB
    __shared__ __attribute__((aligned(16))) u16 B1s[2][64 * 32];   // 8 KB
    __shared__ __attribute__((aligned(16))) u16 B2s[2][64 * 32];   // 8 KB
    const int tid = threadIdx.x;
    const int w = tid >> 6, lane = tid & 63;
    const int quad = lane >> 4, t = lane & 15;
    const int m0 = blockIdx.y * 128, n0 = blockIdx.x * 64;
    const int wm = (w >> 1) * 64, wn = (w & 1) * 32;

    const int srow = w * 16 + (lane >> 2);
    const int scol = (lane & 3) * 8;
    const u16* pA0 = A + (size_t)(m0 + srow) * K + scol;
    const u16* pA1 = pA0 + (size_t)64 * K;
    const u16* pB1 = B1t + (size_t)(n0 + srow) * K + scol;
    const u16* pB2 = B2t + (size_t)(n0 + srow) * K + scol;

    f32x4 acc1[4][2], acc2[4][2];
    #pragma unroll
    for (int i = 0; i < 4; ++i)
        #pragma unroll
        for (int j = 0; j < 2; ++j) {
            acc1[i][j] = (f32x4){0.f, 0.f, 0.f, 0.f};
            acc2[i][j] = (f32x4){0.f, 0.f, 0.f, 0.f};
        }

    for (int kb = 0; kb < K; kb += 64) {
        __syncthreads();
        stage16(pA0 + kb,      (char*)As[0] + w * 1024);
        stage16(pA1 + kb,      (char*)As[0] + 4096 + w * 1024);
        stage16(pB1 + kb,      (char*)B1s[0] + w * 1024);
        stage16(pB2 + kb,      (char*)B2s[0] + w * 1024);
        stage16(pA0 + kb + 32, (char*)As[1] + w * 1024);
        stage16(pA1 + kb + 32, (char*)As[1] + 4096 + w * 1024);
        stage16(pB1 + kb + 32, (char*)B1s[1] + w * 1024);
        stage16(pB2 + kb + 32, (char*)B2s[1] + w * 1024);
        __syncthreads();
        #pragma unroll
        for (int hf = 0; hf < 2; ++hf) {
            bf16x8 af[4], b1r[2], b2r[2];
            #pragma unroll
            for (int mi = 0; mi < 4; ++mi)
                af[mi] = *(const bf16x8*)((char*)As[hf] + (wm + mi * 16 + t) * 64 + quad * 16);
            #pragma unroll
            for (int ni = 0; ni < 2; ++ni) {
                b1r[ni] = *(const bf16x8*)((char*)B1s[hf] + (wn + ni * 16 + t) * 64 + quad * 16);
                b2r[ni] = *(const bf16x8*)((char*)B2s[hf] + (wn + ni * 16 + t) * 64 + quad * 16);
            }
            #pragma unroll
            for (int mi = 0; mi < 4; ++mi)
                #pragma unroll
                for (int ni = 0; ni < 2; ++ni) {
                    acc1[mi][ni] = __builtin_amdgcn_mfma_f32_16x16x32_bf16(af[mi], b1r[ni],
                                                                          acc1[mi][ni], 0, 0, 0);
                    acc2[mi][ni] = __builtin_amdgcn_mfma_f32_16x16x32_bf16(af[mi], b2r[ni],
                                                                          acc2[mi][ni], 0, 0, 0);
                }
        }
    }
    #pragma unroll
    for (int mi = 0; mi < 4; ++mi) {
        const int row0 = m0 + wm + mi * 16 + quad * 4;
        #pragma unroll
        for (int ni = 0; ni < 2; ++ni) {
            const int col = n0 + wn + ni * 16 + t;
            #pragma unroll
            for (int r = 0; r < 4; ++r) {
                const size_t idx = (size_t)(row0 + r) * N + col;
                const float a = acc1[mi][ni][r];
                Cout[idx] = f2b((a / (1.f + __expf(-a))) * acc2[mi][ni][r]);
            }
        }
    }
}

// ---- flash attention: qkv (4096 x 3072 bf16, roped), y (4096 x 1024 bf16) ----
// Pair-balanced (block does q-tiles (31-pairk) then (pairk) = 33 uniform K-tiles)
// + XCD-GROUPED mapping: all 16 blocks of one (h,b) on ONE XCD -> K/V L2-resident
// (FETCH 97 -> 12 MB measured). DPP softmax; diagonal-only mask; folded Q-scale;
// Vts XOR-swizzled.
__global__ __launch_bounds__(256) void attn_kernel(const u16* __restrict__ qkv,
                                                   const int* __restrict__ ymask,
                                                   u16* __restrict__ y) {
    const int gid = blockIdx.x;              // 0..511
    const int xcd = gid & 7;
    const int j2 = gid >> 3;                 // 0..63
    const int slot = j2 >> 4;                // 0..3
    const int pairk = j2 & 15;               // 0..15
    const int group = slot * 8 + xcd;        // 0..31
    const int h = group & 15, b = group >> 4;
    const int tid = threadIdx.x;
    const int w = tid >> 6, lane = tid & 63;
    const int quad = lane >> 4, t = lane & 15;

    __shared__ __attribute__((aligned(16))) u16 Ks[64 * 72];    // [key][d], 144B rows
    __shared__ __attribute__((aligned(16))) u16 Vts[64 * 72];   // [d][key], swizzled
    __shared__ __attribute__((aligned(16))) u16 Ps[4][16 * 72]; // per-wave P [m][key]
    __shared__ int ymL[64];
    if (pairk == 0 && tid < 64) ymL[tid] = ymask[b * 64 + tid];

    // staging assignment: thread -> (key = tid>>3 and +32, dg = tid&7)
    const int skey = tid >> 3, sdg = tid & 7;
    const u16* pK = qkv + (size_t)(b * 2048 + skey) * 3072 + h * 64 + sdg * 8 + 1024;
    const int sblk0 = (skey >> 3) ^ sdg;          // Vts block for keys 0..31 set
    const int sblk1 = (4 + (skey >> 3)) ^ sdg;    // keys 32..63 set

    for (int seg = 0; seg < 2; ++seg) {
        const int qt = seg ? pairk : 31 - pairk;  // long segment first
        const int q0 = qt * 64;

        bf16x8 aQ[2];
        {
            const u16* qp = qkv + (size_t)(b * 2048 + q0 + w * 16 + t) * 3072 + h * 64 + quad * 8;
            aQ[0] = *(const bf16x8*)qp;
            aQ[1] = *(const bf16x8*)(qp + 32);
            #pragma unroll
            for (int i = 0; i < 8; ++i) {   // fold 1/sqrt(64): *2^-3 exact in bf16
                aQ[0][i] = (short)f2b(b2f((u16)aQ[0][i]) * 0.125f);
                aQ[1][i] = (short)f2b(b2f((u16)aQ[1][i]) * 0.125f);
            }
        }

        f32x4 accO[4] = {(f32x4){0,0,0,0},(f32x4){0,0,0,0},(f32x4){0,0,0,0},(f32x4){0,0,0,0}};
        float mOld[4] = {-INFINITY, -INFINITY, -INFINITY, -INFINITY};
        float lSum[4] = {0.f, 0.f, 0.f, 0.f};

        for (int kb = 0; kb <= qt; ++kb) {
            // global loads issued before the barrier (latency overlaps drain)
            const u16* pk = pK + (size_t)kb * 196608;        // kb*64*3072
            const uint4 kv0 = *(const uint4*)pk;
            const uint4 vv0 = *(const uint4*)(pk + 1024);
            const uint4 kv1 = *(const uint4*)(pk + 98304);   // +32*3072
            const uint4 vv1 = *(const uint4*)(pk + 99328);
            __syncthreads();                 // prior iteration's LDS reads done
            *(uint4*)((char*)Ks + skey * 144 + sdg * 16) = kv0;
            *(uint4*)((char*)Ks + (skey + 32) * 144 + sdg * 16) = kv1;
            {
                const u16* vp0 = (const u16*)&vv0;
                const u16* vp1 = (const u16*)&vv1;
                #pragma unroll
                for (int jj = 0; jj < 8; ++jj) {
                    const int row = sdg * 8 + jj;
                    Vts[row * 72 + sblk0 * 8 + (skey & 7)] = vp0[jj];
                    Vts[row * 72 + sblk1 * 8 + (skey & 7)] = vp1[jj];
                }
            }
            __syncthreads();

            float s[4][4];
            __builtin_amdgcn_s_setprio(1);
            #pragma unroll
            for (int ni = 0; ni < 4; ++ni) {
                bf16x8 bK0 = *(const bf16x8*)((char*)Ks + (ni * 16 + t) * 144 + quad * 16);
                bf16x8 bK1 = *(const bf16x8*)((char*)Ks + (ni * 16 + t) * 144 + 64 + quad * 16);
                f32x4 sa = (f32x4){0.f, 0.f, 0.f, 0.f};
                sa = __builtin_amdgcn_mfma_f32_16x16x32_bf16(aQ[0], bK0, sa, 0, 0, 0);
                sa = __builtin_amdgcn_mfma_f32_16x16x32_bf16(aQ[1], bK1, sa, 0, 0, 0);
                #pragma unroll
                for (int r = 0; r < 4; ++r) s[ni][r] = sa[r];
            }
            __builtin_amdgcn_s_setprio(0);

            // mask only on the diagonal tile; ym text-mask only in the qt==0 tile.
            if (kb == qt) {
                const int irow = q0 + w * 16 + quad * 4;
                #pragma unroll
                for (int ni = 0; ni < 4; ++ni)
                    #pragma unroll
                    for (int r = 0; r < 4; ++r) {
                        const int i = irow + r, j = kb * 64 + ni * 16 + t;
                        const bool ok = (j <= i) || (qt == 0 && ymL[i & 63] && ymL[j & 63]);
                        if (!ok) s[ni][r] = -INFINITY;
                    }
            }

            float alpha[4];
            bool upd = false;
            #pragma unroll
            for (int r = 0; r < 4; ++r) {
                float mt = fmaxf(fmaxf(s[0][r], s[1][r]), fmaxf(s[2][r], s[3][r]));
                mt = rowmax16(mt);                       // DPP, VALU-rate
                const float mNew = fmaxf(mOld[r], mt);
                upd = upd || (mNew > mOld[r]);
                alpha[r] = __expf(mOld[r] - mNew);
                #pragma unroll
                for (int ni = 0; ni < 4; ++ni) s[ni][r] = __expf(s[ni][r] - mNew);
                mOld[r] = mNew;
            }

            // P (C-layout) -> per-wave LDS, issued early; ds_write latency hides
            // under the DPP sum-reduces below. Same-wave, no barrier needed.
            u16* Pw = Ps[w];
            #pragma unroll
            for (int ni = 0; ni < 4; ++ni)
                #pragma unroll
                for (int r = 0; r < 4; ++r)
                    Pw[(quad * 4 + r) * 72 + ni * 16 + t] = f2b(s[ni][r]);

            #pragma unroll
            for (int r = 0; r < 4; ++r) {
                float rs = (s[0][r] + s[1][r]) + (s[2][r] + s[3][r]);
                rs = rowsum16(rs);                       // DPP, VALU-rate
                lSum[r] = lSum[r] * alpha[r] + rs;
            }
            if (__any(upd)) {               // skip O-rescale when no row's max moved
                #pragma unroll
                for (int dt = 0; dt < 4; ++dt)
                    #pragma unroll
                    for (int r = 0; r < 4; ++r) accO[dt][r] *= alpha[r];
            }

            bf16x8 aP0 = *(const bf16x8*)((char*)Pw + t * 144 + quad * 16);
            bf16x8 aP1 = *(const bf16x8*)((char*)Pw + t * 144 + 64 + quad * 16);
            __builtin_amdgcn_s_setprio(1);
            #pragma unroll
            for (int dt = 0; dt < 4; ++dt) {
                const int row = dt * 16 + t, rb = row >> 3;
                bf16x8 bV0 = *(const bf16x8*)((char*)Vts + row * 144 + ((quad ^ rb) << 4));
                bf16x8 bV1 = *(const bf16x8*)((char*)Vts + row * 144 + (((4 + quad) ^ rb) << 4));
                accO[dt] = __builtin_amdgcn_mfma_f32_16x16x32_bf16(aP0, bV0, accO[dt], 0, 0, 0);
                accO[dt] = __builtin_amdgcn_mfma_f32_16x16x32_bf16(aP1, bV1, accO[dt], 0, 0, 0);
            }
            __builtin_amdgcn_s_setprio(0);
        }
        const int orow = q0 + w * 16 + quad * 4;
        #pragma unroll
        for (int dt = 0; dt < 4; ++dt)
            #pragma unroll
            for (int r = 0; r < 4; ++r) {
                const size_t idx = (size_t)(b * 2048 + orow + r) * 1024 + h * 64 + dt * 16 + t;
                y[idx] = f2b(accO[dt][r] / lSum[r]);
            }
    }
}

extern "C" void kernel_launch(void* const* d_in, const int* in_sizes, int n_in,
                              void* d_out, int out_size, void* d_ws, size_t ws_size,
                              hipStream_t stream) {
    const float* x     = (const float*)d_in[0];
    const int*   ym    = (const int*)d_in[1];
    const float* Wqkv  = (const float*)d_in[2];
    const float* Wattn = (const float*)d_in[3];
    const float* s1    = (const float*)d_in[4];
    const float* s2    = (const float*)d_in[5];
    const float* Wfc1  = (const float*)d_in[6];
    const float* Wfc2  = (const float*)d_in[7];
    const float* Wmlp  = (const float*)d_in[8];

    char* ws = (char*)d_ws;
    u16*   h    = (u16*)(ws + 0);          // 8 MB bf16; reused as attention output
    u16*   qkv  = (u16*)(ws + 8388608);    // 24 MB bf16; later reused as fc1/m
    u16*   fc1  = qkv;
    float* xr   = (float*)(ws + 33554432); // 16 MB fp32 residual
    u16*   WtA  = (u16*)(ws + 50331648);   // 2 MB
    u16*   WtF1 = (u16*)(ws + 52428800);   // 5.5 MB
    u16*   WtF2 = (u16*)(ws + 58195968);   // 5.5 MB
    u16*   WtM  = (u16*)(ws + 63963136);   // 5.5 MB
    u16*   WtQ  = (u16*)(ws + 73400320);   // 6 MB
    const dim3 tb(32, 8);

    transpose_all<<<12544, tb, 0, stream>>>(Wqkv, Wattn, Wfc1, Wfc2, Wmlp,
                                            WtQ, WtA, WtF1, WtF2, WtM);
    rmsnorm_f32<<<4096, 256, 0, stream>>>(x, s1, h);
    gemm_bt<0><<<dim3(24, 32), 256, 0, stream>>>(h, WtQ, qkv, nullptr, 3072, 1024);
    rope_kernel<<<512, 256, 0, stream>>>(qkv);
    attn_kernel<<<512, 256, 0, stream>>>(qkv, ym, h);   // h dead -> y
    gemm_bt64<1><<<dim3(16, 32), 256, 0, stream>>>(h, WtA, xr, x, 1024, 1024);
    rmsnorm_f32<<<4096, 256, 0, stream>>>(xr, s2, h);
    gemm_fc<<<dim3(44, 32), 256, 0, stream>>>(h, WtF1, WtF2, fc1, 2816, 1024);
    gemm_bt64<1><<<dim3(16, 32), 256, 0, stream>>>(fc1, WtM, (float*)d_out, xr, 1024, 2816);
}